// Round 1
// baseline (67474.591 us; speedup 1.0000x reference)
//
#include <hip/hip_runtime.h>
#include <math.h>

#define BB 128
#define TT 256
#define TMEL 800
#define EE 512
#define HH 1024
#define G4 4096
#define MELD 128
#define VV 256

// ws offsets (in floats)
#define OFF_PROJ 0u
#define OFF_T1   131072u
#define OFF_WR2  524288u
#define OFF_BB1  1310720u
#define OFF_BB2  1311232u
#define OFF_B2   1311744u
#define OFF_W2C  1315840u
#define OFF_HE0  5510144u
#define OFF_HE1  5641216u
#define OFF_CE   5772288u
#define OFF_H2   5903360u
#define OFF_H1P  22680576u

__device__ __forceinline__ float sigm(float x){ return 1.0f/(1.0f+expf(-x)); }

// proj[v][e] = sum_k emb[v][k]*W[e][k] + b[e]
__global__ void k_proj(const float* __restrict__ emb, const float* __restrict__ W,
                       const float* __restrict__ bias, float* __restrict__ proj){
  __shared__ float er[EE];
  int v = blockIdx.x;
  for(int i=threadIdx.x;i<EE;i+=256) er[i]=emb[v*EE+i];
  __syncthreads();
  for(int e=threadIdx.x;e<EE;e+=256){
    const float* wr = W + e*EE;
    float acc=0.f;
    for(int k=0;k<EE;k+=4){
      float4 w4 = *(const float4*)(wr+k);
      acc += er[k]*w4.x + er[k+1]*w4.y + er[k+2]*w4.z + er[k+3]*w4.w;
    }
    proj[v*EE+e] = acc + bias[e];
  }
}

// T1s[v][k3][c] = s1[c] * sum_ci conv1_W[c][ci][k3] * proj[v][ci]
__global__ void k_t1(const float* __restrict__ proj, const float* __restrict__ W1,
                     const float* __restrict__ g1, float* __restrict__ T1){
  __shared__ float pr[EE];
  int v = blockIdx.x; int k3 = blockIdx.y;
  for(int i=threadIdx.x;i<EE;i+=256) pr[i]=proj[v*EE+i];
  __syncthreads();
  const float s = rsqrtf(1.f+1e-5f);
  for(int c=threadIdx.x;c<EE;c+=256){
    float acc=0.f;
    const float* w = W1 + c*EE*3 + k3;
    for(int ci=0;ci<EE;ci++) acc += pr[ci]*w[ci*3];
    T1[(v*3+k3)*EE+c] = g1[c]*s*acc;
  }
}

// Wr2s[c][k3*512+ci] = s2[c]*conv2_W[c][ci][k3]
__global__ void k_wr2(const float* __restrict__ W2, const float* __restrict__ g2, float* __restrict__ Wr){
  int idx = blockIdx.x*256+threadIdx.x;
  if(idx >= EE*3*EE) return;
  int c = idx/1536; int r = idx%1536; int k3 = r/EE; int ci = r%EE;
  const float s = rsqrtf(1.f+1e-5f);
  Wr[idx] = g2[c]*s*W2[(c*EE+ci)*3+k3];
}

__global__ void k_bb(const float* __restrict__ b1,const float* __restrict__ g1,const float* __restrict__ be1,
                     const float* __restrict__ b2,const float* __restrict__ g2,const float* __restrict__ be2,
                     float* __restrict__ bb1, float* __restrict__ bb2){
  int c = threadIdx.x + blockIdx.x*256; if(c>=EE) return;
  const float s = rsqrtf(1.f+1e-5f);
  bb1[c] = g1[c]*s*b1[c] + be1[c];
  bb2[c] = g2[c]*s*b2[c] + be2[c];
}

// b2[j] = b_d[j] + sum_m Wih_d[j][m]*bp[m]
__global__ void k_b2(const float* __restrict__ bd, const float* __restrict__ Wih,
                     const float* __restrict__ bp, float* __restrict__ b2){
  int j = blockIdx.x*256+threadIdx.x; if(j>=G4) return;
  float acc = bd[j];
  const float* w = Wih + j*MELD;
  for(int m=0;m<MELD;m++) acc += w[m]*bp[m];
  b2[j] = acc;
}

// W2c[j][k] = Whh_d[j][k] + sum_m Wih_d[j][m]*Wp[m][k]
__global__ void k_w2c(const float* __restrict__ Whh, const float* __restrict__ Wih,
                      const float* __restrict__ Wp, float* __restrict__ W2c){
  __shared__ float wl[8][MELD];
  int j0 = blockIdx.x*8; int k = blockIdx.y*256 + threadIdx.x;
  for(int i=threadIdx.x;i<8*MELD;i+=256) wl[i/MELD][i%MELD] = Wih[(j0+i/MELD)*MELD + (i%MELD)];
  __syncthreads();
  float acc[8];
  #pragma unroll
  for(int jj=0;jj<8;jj++) acc[jj]=Whh[(j0+jj)*HH+k];
  for(int m=0;m<MELD;m++){
    float wp = Wp[m*HH+k];
    #pragma unroll
    for(int jj=0;jj<8;jj++) acc[jj] += wl[jj][m]*wp;
  }
  #pragma unroll
  for(int jj=0;jj<8;jj++) W2c[(j0+jj)*HH+k] = acc[jj];
}

// zero padding rows of h1p
__global__ void k_pad(float* __restrict__ h1p){
  int idx = blockIdx.x*256+threadIdx.x;
  int c = idx & (EE-1); int b = idx >> 9;
  h1p[(size_t)(b*(TT+2))*EE + c] = 0.f;
  h1p[(size_t)(b*(TT+2)+TT+1)*EE + c] = 0.f;
}

// h1p[b][t+1][c] = relu(bb1[c] + sum_k T1[x[b][t-1+k]][k][c])
__global__ void k_conv1(const int* __restrict__ x, const float* __restrict__ T1,
                        const float* __restrict__ bb1, float* __restrict__ h1p){
  int idx = blockIdx.x*256+threadIdx.x;
  int c = idx & (EE-1); int bt = idx >> 9; int t = bt & (TT-1); int b = bt >> 8;
  float acc = bb1[c];
  if(t > 0)    acc += T1[(size_t)(x[b*TT+t-1]*3+0)*EE+c];
               acc += T1[(size_t)(x[b*TT+t  ]*3+1)*EE+c];
  if(t < TT-1) acc += T1[(size_t)(x[b*TT+t+1]*3+2)*EE+c];
  h1p[(size_t)(b*(TT+2) + t + 1)*EE + c] = fmaxf(acc, 0.f);
}

// conv2 as tiled GEMM: h2[b][t][c] = relu(bb2[c] + A(h1p rows t..t+2) . Wr2s[c])
__global__ __launch_bounds__(256) void k_conv2(const float* __restrict__ h1p, const float* __restrict__ Wr,
                        const float* __restrict__ bb2, float* __restrict__ h2){
  __shared__ float As[64][128];
  __shared__ float Ws[64][16];
  int mt = blockIdx.x;   // 0..255
  int nt = blockIdx.y;   // 0..31
  int b = mt>>1; int t0 = (mt&1)*128;
  int tid = threadIdx.x;
  int tm = tid>>3, tn = tid&7;
  float acc[4][2]={};
  int rb = tid&127; int kh=(tid>>7)*32;
  const float* arow = h1p + (size_t)(b*(TT+2) + t0 + rb)*EE; // K=1536 contiguous
  int wn = tid&15; int wk = (tid>>4)*4;
  const float* wrow = Wr + (size_t)(nt*16+wn)*1536;
  for(int kc=0;kc<1536;kc+=64){
    #pragma unroll
    for(int i=0;i<8;i++){
      int k = kh + i*4;
      float4 a = *(const float4*)(arow + kc + k);
      As[k][rb]=a.x; As[k+1][rb]=a.y; As[k+2][rb]=a.z; As[k+3][rb]=a.w;
    }
    {
      float4 w = *(const float4*)(wrow + kc + wk);
      Ws[wk][wn]=w.x; Ws[wk+1][wn]=w.y; Ws[wk+2][wn]=w.z; Ws[wk+3][wn]=w.w;
    }
    __syncthreads();
    #pragma unroll
    for(int k=0;k<64;k++){
      float4 a = *(const float4*)&As[k][tm*4];
      float2 w = *(const float2*)&Ws[k][tn*2];
      acc[0][0]+=a.x*w.x; acc[0][1]+=a.x*w.y;
      acc[1][0]+=a.y*w.x; acc[1][1]+=a.y*w.y;
      acc[2][0]+=a.z*w.x; acc[2][1]+=a.z*w.y;
      acc[3][0]+=a.w*w.x; acc[3][1]+=a.w*w.y;
    }
    __syncthreads();
  }
  #pragma unroll
  for(int i=0;i<4;i++){
    int t = t0+tm*4+i;
    #pragma unroll
    for(int j=0;j<2;j++){
      int c = nt*16+tn*2+j;
      h2[(size_t)(b*TT+t)*EE + c] = fmaxf(acc[i][j]+bb2[c], 0.f);
    }
  }
}

// encoder step: WG w owns h-cols [w*4, w*4+4); computes 16 gate cols (4 gates x 4 cols), K=1536
__global__ __launch_bounds__(256) void k_enc(const float* __restrict__ h2, const float* __restrict__ hin,
   float* __restrict__ hout, float* __restrict__ ce,
   const float* __restrict__ Wih, const float* __restrict__ Whh, const float* __restrict__ be,
   const int* __restrict__ lens, int t){
  __shared__ float As[64][128];
  __shared__ float Ws[64][16];
  int w = blockIdx.x;
  int tid = threadIdx.x;
  int tm=tid>>3, tn=tid&7;
  float acc[4][2]={};
  int rb=tid&127, kh=(tid>>7)*32;
  int wn=tid&15, wk=(tid>>4)*4;
  int gg=wn>>2, jh=wn&3;
  int wcol = gg*HH + w*4 + jh;
  for(int kc=0;kc<EE+HH;kc+=64){
    #pragma unroll
    for(int i=0;i<8;i++){
      int k=kh+i*4; int gk = kc+k;
      float4 a = (gk < EE) ? *(const float4*)(h2 + (size_t)(rb*TT+t)*EE + gk)
                           : *(const float4*)(hin + (size_t)rb*HH + (gk-EE));
      As[k][rb]=a.x; As[k+1][rb]=a.y; As[k+2][rb]=a.z; As[k+3][rb]=a.w;
    }
    {
      int gk=kc+wk;
      float4 wv = (gk<EE)? *(const float4*)(Wih + (size_t)wcol*EE + gk)
                         : *(const float4*)(Whh + (size_t)wcol*HH + (gk-EE));
      Ws[wk][wn]=wv.x; Ws[wk+1][wn]=wv.y; Ws[wk+2][wn]=wv.z; Ws[wk+3][wn]=wv.w;
    }
    __syncthreads();
    #pragma unroll
    for(int k=0;k<64;k++){
      float4 a = *(const float4*)&As[k][tm*4];
      float2 wv= *(const float2*)&Ws[k][tn*2];
      acc[0][0]+=a.x*wv.x; acc[0][1]+=a.x*wv.y;
      acc[1][0]+=a.y*wv.x; acc[1][1]+=a.y*wv.y;
      acc[2][0]+=a.z*wv.x; acc[2][1]+=a.z*wv.y;
      acc[3][0]+=a.w*wv.x; acc[3][1]+=a.w*wv.y;
    }
    __syncthreads();
  }
  float (*Gs)[16] = (float(*)[16])(&As[0][0]);
  #pragma unroll
  for(int i=0;i<4;i++){
    #pragma unroll
    for(int j=0;j<2;j++) Gs[tm*4+i][tn*2+j]=acc[i][j];
  }
  __syncthreads();
  #pragma unroll
  for(int p0=0;p0<2;p0++){
    int p = tid + p0*256;
    int jj = p>>7; int b = p&127;
    int hcol = w*4+jj;
    float gi = Gs[b][0*4+jj] + be[0*HH+hcol];
    float gf = Gs[b][1*4+jj] + be[1*HH+hcol];
    float gc = Gs[b][2*4+jj] + be[2*HH+hcol];
    float go = Gs[b][3*4+jj] + be[3*HH+hcol];
    float cold = ce[b*HH+hcol];
    float hold = hin[b*HH+hcol];
    float c2 = sigm(gf)*cold + sigm(gi)*tanhf(gc);
    float h2n = sigm(go)*tanhf(c2);
    bool valid = t < lens[b];
    hout[b*HH+hcol] = valid ? h2n : hold;
    ce[b*HH+hcol]   = valid ? c2  : cold;
  }
}

// decoder step: K=1024 with combined weights (mel feedback folded in)
__global__ __launch_bounds__(256) void k_dec(const float* __restrict__ hin, float* __restrict__ hout,
    float* __restrict__ cd, const float* __restrict__ W, const float* __restrict__ bias){
  __shared__ float As[64][128];
  __shared__ float Ws[64][16];
  int w = blockIdx.x;
  int tid = threadIdx.x;
  int tm=tid>>3, tn=tid&7;
  float acc[4][2]={};
  int rb=tid&127, kh=(tid>>7)*32;
  int wn=tid&15, wk=(tid>>4)*4;
  int gg=wn>>2, jh=wn&3;
  int wcol = gg*HH + w*4 + jh;
  const float* arow = hin + (size_t)rb*HH;
  const float* wrow = W + (size_t)wcol*HH;
  for(int kc=0;kc<HH;kc+=64){
    #pragma unroll
    for(int i=0;i<8;i++){
      int k=kh+i*4;
      float4 a = *(const float4*)(arow + kc + k);
      As[k][rb]=a.x; As[k+1][rb]=a.y; As[k+2][rb]=a.z; As[k+3][rb]=a.w;
    }
    {
      float4 wv = *(const float4*)(wrow + kc + wk);
      Ws[wk][wn]=wv.x; Ws[wk+1][wn]=wv.y; Ws[wk+2][wn]=wv.z; Ws[wk+3][wn]=wv.w;
    }
    __syncthreads();
    #pragma unroll
    for(int k=0;k<64;k++){
      float4 a = *(const float4*)&As[k][tm*4];
      float2 wv= *(const float2*)&Ws[k][tn*2];
      acc[0][0]+=a.x*wv.x; acc[0][1]+=a.x*wv.y;
      acc[1][0]+=a.y*wv.x; acc[1][1]+=a.y*wv.y;
      acc[2][0]+=a.z*wv.x; acc[2][1]+=a.z*wv.y;
      acc[3][0]+=a.w*wv.x; acc[3][1]+=a.w*wv.y;
    }
    __syncthreads();
  }
  float (*Gs)[16] = (float(*)[16])(&As[0][0]);
  #pragma unroll
  for(int i=0;i<4;i++){
    #pragma unroll
    for(int j=0;j<2;j++) Gs[tm*4+i][tn*2+j]=acc[i][j];
  }
  __syncthreads();
  #pragma unroll
  for(int p0=0;p0<2;p0++){
    int p = tid + p0*256;
    int jj = p>>7; int b = p&127;
    int hcol = w*4+jj;
    float gi = Gs[b][0*4+jj] + bias[0*HH+hcol];
    float gf = Gs[b][1*4+jj] + bias[1*HH+hcol];
    float gc = Gs[b][2*4+jj] + bias[2*HH+hcol];
    float go = Gs[b][3*4+jj] + bias[3*HH+hcol];
    float cold = cd[b*HH+hcol];
    float c2 = sigm(gf)*cold + sigm(gi)*tanhf(gc);
    float h2n = sigm(go)*tanhf(c2);
    hout[b*HH+hcol] = h2n;
    cd[b*HH+hcol]   = c2;
  }
}

// post-hoc mel/gate for a 100-step chunk from the h ring; writes masked outputs
__global__ __launch_bounds__(256) void k_chunk(const float* __restrict__ ring, const float* __restrict__ Wp,
    const float* __restrict__ bp, const float* __restrict__ Wg, const float* __restrict__ bg,
    const int* __restrict__ mlen, float* __restrict__ outmel, float* __restrict__ outgate, int tbase){
  __shared__ float As[64][128];
  __shared__ float Ws[64][16];
  int slot = blockIdx.x;  // 0..99
  int nt = blockIdx.y;    // 0..8
  int tid=threadIdx.x; int tm=tid>>3, tn=tid&7;
  float acc[4][2]={};
  int rb=tid&127, kh=(tid>>7)*32;
  int wn=tid&15, wk=(tid>>4)*4;
  int ncol = nt*16+wn;
  const float* wrow = (ncol<MELD)? (Wp + (size_t)ncol*HH) : Wg;
  const float* arow = ring + (size_t)(slot*BB + rb)*HH;
  for(int kc=0;kc<HH;kc+=64){
    #pragma unroll
    for(int i=0;i<8;i++){
      int k=kh+i*4;
      float4 a = *(const float4*)(arow + kc + k);
      As[k][rb]=a.x; As[k+1][rb]=a.y; As[k+2][rb]=a.z; As[k+3][rb]=a.w;
    }
    {
      float4 wv = *(const float4*)(wrow + kc + wk);
      Ws[wk][wn]=wv.x; Ws[wk+1][wn]=wv.y; Ws[wk+2][wn]=wv.z; Ws[wk+3][wn]=wv.w;
    }
    __syncthreads();
    #pragma unroll
    for(int k=0;k<64;k++){
      float4 a = *(const float4*)&As[k][tm*4];
      float2 wv= *(const float2*)&Ws[k][tn*2];
      acc[0][0]+=a.x*wv.x; acc[0][1]+=a.x*wv.y;
      acc[1][0]+=a.y*wv.x; acc[1][1]+=a.y*wv.y;
      acc[2][0]+=a.z*wv.x; acc[2][1]+=a.z*wv.y;
      acc[3][0]+=a.w*wv.x; acc[3][1]+=a.w*wv.y;
    }
    __syncthreads();
  }
  int t = tbase + slot;
  #pragma unroll
  for(int i=0;i<4;i++){
    int b = tm*4+i;
    bool msk = t > mlen[b];
    #pragma unroll
    for(int j=0;j<2;j++){
      int n = nt*16+tn*2+j;
      if(n < MELD){
        float v = acc[i][j]+bp[n];
        outmel[(size_t)(b*TMEL + t)*MELD + n] = msk ? 0.f : v;
      } else if(n==MELD){
        float v = acc[i][j]+bg[0];
        outgate[b*TMEL+t] = msk ? 1000.f : v;
      }
    }
  }
}

__global__ void k_mask(const int* __restrict__ mlen, float* __restrict__ om){
  int idx=blockIdx.x*256+threadIdx.x; if(idx>=BB*TMEL) return;
  int b=idx/TMEL, t=idx%TMEL;
  om[idx] = (t > mlen[b]) ? 1.f : 0.f;
}

extern "C" void kernel_launch(void* const* d_in, const int* in_sizes, int n_in,
                              void* d_out, int out_size, void* d_ws, size_t ws_size,
                              hipStream_t stream){
  (void)in_sizes; (void)n_in; (void)out_size; (void)ws_size;
  const int*   x    = (const int*)d_in[0];
  const int*   tlen = (const int*)d_in[1];
  const int*   mlen = (const int*)d_in[3];
  const float* emb  = (const float*)d_in[4];
  const float* elW  = (const float*)d_in[5];
  const float* elb  = (const float*)d_in[6];
  const float* c1W  = (const float*)d_in[7];
  const float* c1b  = (const float*)d_in[8];
  const float* g1   = (const float*)d_in[9];
  const float* be1  = (const float*)d_in[10];
  const float* c2W  = (const float*)d_in[11];
  const float* c2b  = (const float*)d_in[12];
  const float* g2   = (const float*)d_in[13];
  const float* be2  = (const float*)d_in[14];
  const float* Wihe = (const float*)d_in[15];
  const float* Whhe = (const float*)d_in[16];
  const float* bhe  = (const float*)d_in[17];
  const float* Wihd = (const float*)d_in[18];
  const float* Whhd = (const float*)d_in[19];
  const float* bhd  = (const float*)d_in[20];
  const float* Wp   = (const float*)d_in[21];
  const float* bp   = (const float*)d_in[22];
  const float* Wg   = (const float*)d_in[23];
  const float* bg   = (const float*)d_in[24];

  float* ws   = (float*)d_ws;
  float* proj = ws + OFF_PROJ;
  float* T1   = ws + OFF_T1;
  float* Wr2  = ws + OFF_WR2;
  float* bb1  = ws + OFF_BB1;
  float* bb2  = ws + OFF_BB2;
  float* b2   = ws + OFF_B2;
  float* W2c  = ws + OFF_W2C;
  float* he0  = ws + OFF_HE0;
  float* he1  = ws + OFF_HE1;
  float* ce   = ws + OFF_CE;
  float* h2   = ws + OFF_H2;
  float* h1p  = ws + OFF_H1P;
  float* ring = h1p;  // reuse after conv2 is done

  float* outmel  = (float*)d_out;
  float* outgate = outmel + (size_t)BB*TMEL*MELD;
  float* outmask = outgate + (size_t)BB*TMEL;

  // zero h/c state (he0, he1, ce contiguous)
  hipMemsetAsync(he0, 0, (size_t)3*BB*HH*sizeof(float), stream);

  k_proj<<<VV,256,0,stream>>>(emb, elW, elb, proj);
  k_t1<<<dim3(VV,3),256,0,stream>>>(proj, c1W, g1, T1);
  k_wr2<<<(EE*3*EE+255)/256,256,0,stream>>>(c2W, g2, Wr2);
  k_bb<<<2,256,0,stream>>>(c1b,g1,be1,c2b,g2,be2,bb1,bb2);
  k_b2<<<16,256,0,stream>>>(bhd, Wihd, bp, b2);
  k_w2c<<<dim3(G4/8,HH/256),256,0,stream>>>(Whhd, Wihd, Wp, W2c);
  k_pad<<<256,256,0,stream>>>(h1p);
  k_conv1<<<65536,256,0,stream>>>(x, T1, bb1, h1p);
  k_conv2<<<dim3(256,32),256,0,stream>>>(h1p, Wr2, bb2, h2);

  for(int t=0;t<TT;t++){
    const float* hin = (t&1)? he1 : he0;
    float* hout = (t&1)? he0 : he1;
    k_enc<<<256,256,0,stream>>>(h2, hin, hout, ce, Wihe, Whhe, bhe, tlen, t);
  }
  // final encoder state: h in he0 (t=255 odd -> wrote he0), c in ce

  for(int t=0;t<TMEL;t++){
    const float* hin = (t==0)? he0 : (ring + (size_t)((t-1)%100)*BB*HH);
    float* hout = ring + (size_t)(t%100)*BB*HH;
    const float* Wsel = (t==0)? Whhd : W2c;
    const float* bsel = (t==0)? bhd : b2;
    k_dec<<<256,256,0,stream>>>(hin, hout, ce, Wsel, bsel);
    if((t%100)==99){
      k_chunk<<<dim3(100,9),256,0,stream>>>(ring, Wp, bp, Wg, bg, mlen, outmel, outgate, t-99);
    }
  }
  k_mask<<<(BB*TMEL+255)/256,256,0,stream>>>(mlen, outmask);
}

// Round 2
// 45797.543 us; speedup vs baseline: 1.4733x; 1.4733x over previous
//
#include <hip/hip_runtime.h>
#include <hip/hip_cooperative_groups.h>
#include <math.h>

namespace cg = cooperative_groups;

#define BB 128
#define TT 256
#define TMEL 800
#define EE 512
#define HH 1024
#define G4 4096
#define MELD 128
#define VV 256

// ws offsets (float units)
#define OFF_PROJ  0u
#define OFF_T1    131072u
#define OFF_WR2   524288u
#define OFF_BB1   1310720u
#define OFF_BB2   1311232u
#define OFF_B2    1311744u
#define OFF_W2C   1315840u
#define OFF_BENC  5510144u
#define OFF_B2P   5514240u
#define OFF_BD0   5518336u
#define OFF_BPG   5522432u
#define OFF_WENCP 5522688u
#define OFF_W2CP  8668416u
#define OFF_WHHDP 10765568u
#define OFF_WPGP  12862720u
#define OFF_H2B   12936448u
#define OFF_H1PB  21325056u   /* ring aliases this after conv2 */

typedef __bf16 bfv8 __attribute__((ext_vector_type(8)));
typedef float f32x4 __attribute__((ext_vector_type(4)));

__device__ __forceinline__ unsigned short f2b(float f){
  union { float f; unsigned u; } v; v.f = f;
  unsigned u = v.u;
  return (unsigned short)((u + 0x7fffu + ((u>>16)&1u)) >> 16);
}
__device__ __forceinline__ float sigm(float x){ return 1.0f/(1.0f+expf(-x)); }

__device__ __forceinline__ f32x4 mfma16(bfv8 a, bfv8 b, f32x4 c){
  return __builtin_amdgcn_mfma_f32_16x16x32_bf16(a, b, c, 0, 0, 0);
}

// ---- fp32 precompute kernels ----

__global__ void k_proj(const float* __restrict__ emb, const float* __restrict__ W,
                       const float* __restrict__ bias, float* __restrict__ proj){
  __shared__ float er[EE];
  int v = blockIdx.x;
  for(int i=threadIdx.x;i<EE;i+=256) er[i]=emb[v*EE+i];
  __syncthreads();
  for(int e=threadIdx.x;e<EE;e+=256){
    const float* wr = W + e*EE;
    float acc=0.f;
    for(int k=0;k<EE;k+=4){
      float4 w4 = *(const float4*)(wr+k);
      acc += er[k]*w4.x + er[k+1]*w4.y + er[k+2]*w4.z + er[k+3]*w4.w;
    }
    proj[v*EE+e] = acc + bias[e];
  }
}

__global__ void k_t1(const float* __restrict__ proj, const float* __restrict__ W1,
                     const float* __restrict__ g1, float* __restrict__ T1){
  __shared__ float pr[EE];
  int v = blockIdx.x; int k3 = blockIdx.y;
  for(int i=threadIdx.x;i<EE;i+=256) pr[i]=proj[v*EE+i];
  __syncthreads();
  const float s = rsqrtf(1.f+1e-5f);
  for(int c=threadIdx.x;c<EE;c+=256){
    float acc=0.f;
    const float* w = W1 + c*EE*3 + k3;
    for(int ci=0;ci<EE;ci++) acc += pr[ci]*w[ci*3];
    T1[(v*3+k3)*EE+c] = g1[c]*s*acc;
  }
}

__global__ void k_wr2(const float* __restrict__ W2, const float* __restrict__ g2,
                      unsigned short* __restrict__ Wr){
  int idx = blockIdx.x*256+threadIdx.x;
  if(idx >= EE*3*EE) return;
  int c = idx/1536; int r = idx%1536; int k3 = r/EE; int ci = r%EE;
  const float s = rsqrtf(1.f+1e-5f);
  Wr[idx] = f2b(g2[c]*s*W2[(c*EE+ci)*3+k3]);
}

__global__ void k_bb(const float* __restrict__ b1,const float* __restrict__ g1,const float* __restrict__ be1,
                     const float* __restrict__ b2,const float* __restrict__ g2,const float* __restrict__ be2,
                     float* __restrict__ bb1, float* __restrict__ bb2){
  int c = threadIdx.x + blockIdx.x*256; if(c>=EE) return;
  const float s = rsqrtf(1.f+1e-5f);
  bb1[c] = g1[c]*s*b1[c] + be1[c];
  bb2[c] = g2[c]*s*b2[c] + be2[c];
}

__global__ void k_b2(const float* __restrict__ bd, const float* __restrict__ Wih,
                     const float* __restrict__ bp, float* __restrict__ b2){
  int j = blockIdx.x*256+threadIdx.x; if(j>=G4) return;
  float acc = bd[j];
  const float* w = Wih + j*MELD;
  for(int m=0;m<MELD;m++) acc += w[m]*bp[m];
  b2[j] = acc;
}

__global__ void k_w2c(const float* __restrict__ Whh, const float* __restrict__ Wih,
                      const float* __restrict__ Wp, float* __restrict__ W2c){
  __shared__ float wl[8][MELD];
  int j0 = blockIdx.x*8; int k = blockIdx.y*256 + threadIdx.x;
  for(int i=threadIdx.x;i<8*MELD;i+=256) wl[i/MELD][i%MELD] = Wih[(j0+i/MELD)*MELD + (i%MELD)];
  __syncthreads();
  float acc[8];
  #pragma unroll
  for(int jj=0;jj<8;jj++) acc[jj]=Whh[(j0+jj)*HH+k];
  for(int m=0;m<MELD;m++){
    float wp = Wp[m*HH+k];
    #pragma unroll
    for(int jj=0;jj<8;jj++) acc[jj] += wl[jj][m]*wp;
  }
  #pragma unroll
  for(int jj=0;jj<8;jj++) W2c[(j0+jj)*HH+k] = acc[jj];
}

// ---- packing to bf16 (WG w owns h-cols [w*4,w*4+4), 16 packed rows r=g*4+jh) ----
__device__ __forceinline__ int srow_map(int pr){
  int r = pr & 15;
  return (r>>2)*HH + (pr>>4)*4 + (r&3);
}

__global__ void k_pack_enc(const float* __restrict__ Wihe, const float* __restrict__ Whhe,
                           const float* __restrict__ be,
                           unsigned short* __restrict__ WencP, float* __restrict__ bencP){
  int pr = blockIdx.x; int s = srow_map(pr);
  for(int k=threadIdx.x;k<1536;k+=256){
    float v = (k<EE)? Wihe[(size_t)s*EE+k] : Whhe[(size_t)s*HH + (k-EE)];
    WencP[(size_t)pr*1536+k] = f2b(v);
  }
  if(threadIdx.x==0) bencP[pr] = be[s];
}

__global__ void k_pack_dec(const float* __restrict__ W2c, const float* __restrict__ Whhd,
                           const float* __restrict__ b2, const float* __restrict__ bd,
                           unsigned short* __restrict__ W2cP, unsigned short* __restrict__ WhhdP,
                           float* __restrict__ b2P, float* __restrict__ bd0P){
  int pr = blockIdx.x; int s = srow_map(pr);
  for(int k=threadIdx.x;k<HH;k+=256){
    W2cP[(size_t)pr*HH+k]  = f2b(W2c[(size_t)s*HH+k]);
    WhhdP[(size_t)pr*HH+k] = f2b(Whhd[(size_t)s*HH+k]);
  }
  if(threadIdx.x==0){ b2P[pr]=b2[s]; bd0P[pr]=bd[s]; }
}

__global__ void k_pack_pg(const float* __restrict__ Wp, const float* __restrict__ Wg,
                          const float* __restrict__ bp, const float* __restrict__ bg,
                          unsigned short* __restrict__ WpgP, float* __restrict__ bpg){
  int n = blockIdx.x;  // 0..143
  for(int k=threadIdx.x;k<HH;k+=256){
    float v = (n<MELD)? Wp[(size_t)n*HH+k] : (n==MELD? Wg[k] : 0.f);
    WpgP[(size_t)n*HH+k] = f2b(v);
  }
  if(threadIdx.x==0 && n<=MELD) bpg[n] = (n<MELD)? bp[n] : bg[0];
}

// ---- conv path (bf16 h1 buffer, padded rows) ----

__global__ void k_pad(unsigned short* __restrict__ h1pb){
  int idx = blockIdx.x*256+threadIdx.x; // 65536
  int c = idx & 511; int b = idx >> 9;
  h1pb[((size_t)b*258)*EE + c] = 0;
  h1pb[((size_t)b*258 + 257)*EE + c] = 0;
}

__global__ void k_conv1(const int* __restrict__ x, const float* __restrict__ T1,
                        const float* __restrict__ bb1, unsigned short* __restrict__ h1pb){
  int idx = blockIdx.x*256+threadIdx.x;
  int c = idx & 511; int bt = idx >> 9; int t = bt & 255; int b = bt >> 8;
  float acc = bb1[c];
  if(t > 0)    acc += T1[(size_t)(x[b*TT+t-1]*3+0)*EE+c];
               acc += T1[(size_t)(x[b*TT+t  ]*3+1)*EE+c];
  if(t < TT-1) acc += T1[(size_t)(x[b*TT+t+1]*3+2)*EE+c];
  h1pb[((size_t)b*258 + t + 1)*EE + c] = f2b(fmaxf(acc, 0.f));
}

// ---- MFMA helpers ----

// B streamed from global; A rows stride lda; 2 M-tiles per wave (rows wv*32.. +31)
template<int NKT>
__device__ __forceinline__ void mm_seg_stream(const unsigned short* A, int lda,
    const unsigned short* Wrow, f32x4& acc0, f32x4& acc1, int l, int wv){
  int r0 = wv*32 + (l&15);
  int k8 = (l>>4)*8;
  const unsigned short* a0 = A + (size_t)r0*lda + k8;
  const unsigned short* a1 = a0 + 16*lda;
  const unsigned short* wp = Wrow + k8;
  #pragma unroll
  for(int kt=0;kt<NKT;kt++){
    bfv8 bv = *(const bfv8*)(const void*)(wp + kt*32);
    acc0 = mfma16(*(const bfv8*)(const void*)(a0 + kt*32), bv, acc0);
    acc1 = mfma16(*(const bfv8*)(const void*)(a1 + kt*32), bv, acc1);
  }
}

// B from register array
template<int NKT>
__device__ __forceinline__ void mm_seg(const unsigned short* A, int lda, const bfv8* bf,
    f32x4& acc0, f32x4& acc1, int l, int wv){
  int r0 = wv*32 + (l&15);
  int k8 = (l>>4)*8;
  const unsigned short* a0 = A + (size_t)r0*lda + k8;
  const unsigned short* a1 = a0 + 16*lda;
  #pragma unroll
  for(int kt=0;kt<NKT;kt++){
    acc0 = mfma16(*(const bfv8*)(const void*)(a0 + kt*32), bf[kt], acc0);
    acc1 = mfma16(*(const bfv8*)(const void*)(a1 + kt*32), bf[kt], acc1);
  }
}

__device__ __forceinline__ void store_g(f32x4 a0, f32x4 a1, float (*Gs)[17], int l, int wv){
  int rr = (l>>4)*4, cc = l&15;
  #pragma unroll
  for(int q=0;q<4;q++){
    Gs[wv*32 + rr + q][cc]      = a0[q];
    Gs[wv*32 + 16 + rr + q][cc] = a1[q];
  }
}

// conv2 as bf16 MFMA GEMM: out h2b[t][b][c], K=1536 (3 rows of h1pb)
__global__ __launch_bounds__(256,2) void k_conv2mm(const unsigned short* __restrict__ h1pb,
    const unsigned short* __restrict__ Wr2b, const float* __restrict__ bb2,
    unsigned short* __restrict__ h2b){
  int b = blockIdx.x;    // 0..127
  int th = blockIdx.y;   // 0..1
  int nt = blockIdx.z;   // 0..31
  int tid=threadIdx.x; int wv=tid>>6, l=tid&63;
  const unsigned short* A = h1pb + ((size_t)b*258 + th*128)*EE;
  const unsigned short* Wrow = Wr2b + (size_t)(nt*16+(l&15))*1536;
  f32x4 acc0={0,0,0,0}, acc1={0,0,0,0};
  mm_seg_stream<48>(A, EE, Wrow, acc0, acc1, l, wv);
  int rr=(l>>4)*4, cc=l&15;
  int n = nt*16+cc;
  float bias = bb2[n];
  #pragma unroll
  for(int mi=0;mi<2;mi++){
    f32x4 acc = mi?acc1:acc0;
    int tb = th*128 + wv*32 + mi*16 + rr;
    #pragma unroll
    for(int q=0;q<4;q++){
      float v = fmaxf(acc[q]+bias, 0.f);
      h2b[((size_t)(tb+q)*BB + b)*EE + n] = f2b(v);
    }
  }
}

// ---- LSTM elementwise update (tid<128: one batch row, 4 h-cols) ----
__device__ __forceinline__ void lstm_update(float (*Gs)[17], float (*cst)[4], const float* bP,
    const unsigned short* hin, unsigned short* hout, const int* lens, int t, int w, int tid){
  if(tid >= BB) return;
  int b = tid;
  bool valid = lens ? (t < lens[b]) : true;
  ushort4 hov = *(const ushort4*)(hin + (size_t)b*HH + w*4);
  unsigned short ho[4] = {hov.x, hov.y, hov.z, hov.w};
  unsigned short hn[4];
  #pragma unroll
  for(int jh=0;jh<4;jh++){
    float gi = Gs[b][jh]    + bP[jh];
    float gf = Gs[b][4+jh]  + bP[4+jh];
    float gc = Gs[b][8+jh]  + bP[8+jh];
    float go = Gs[b][12+jh] + bP[12+jh];
    float cold = cst[b][jh];
    float c2 = sigm(gf)*cold + sigm(gi)*tanhf(gc);
    float h2 = sigm(go)*tanhf(c2);
    if(valid) cst[b][jh] = c2;
    hn[jh] = valid ? f2b(h2) : ho[jh];
  }
  *(ushort4*)(hout + (size_t)b*HH + w*4) = make_ushort4(hn[0],hn[1],hn[2],hn[3]);
}

// ---- post-hoc mel/gate chunk (100 slots x 9 n-tiles = 900 tiles over 256 WGs) ----
__device__ __forceinline__ void chunk_proj(const unsigned short* ring, const unsigned short* WpgP,
    const float* bpg, const int* mlen, float* outmel, float* outgate, int tbase,
    int w, int l, int wv){
  for(int tt=w; tt<900; tt+=256){
    int slot = tt/9, nt = tt - slot*9;
    const unsigned short* A = ring + (size_t)slot*BB*HH;
    const unsigned short* Wrow = WpgP + (size_t)(nt*16 + (l&15))*HH;
    f32x4 acc0={0,0,0,0}, acc1={0,0,0,0};
    mm_seg_stream<32>(A, HH, Wrow, acc0, acc1, l, wv);
    int t = tbase + slot;
    int cc = l&15, n = nt*16 + cc;
    #pragma unroll
    for(int mi=0;mi<2;mi++){
      f32x4 acc = mi ? acc1 : acc0;
      int b0 = wv*32 + mi*16 + (l>>4)*4;
      #pragma unroll
      for(int q=0;q<4;q++){
        int b = b0+q;
        bool msk = t > mlen[b];
        if(n < MELD) outmel[((size_t)b*TMEL + t)*MELD + n] = msk ? 0.f : (acc[q]+bpg[n]);
        else if(n==MELD) outgate[(size_t)b*TMEL + t] = msk ? 1000.f : (acc[q]+bpg[MELD]);
      }
    }
  }
}

// ---- the persistent cooperative recurrence kernel ----
__global__ __launch_bounds__(256,1) void k_recur(
  const unsigned short* __restrict__ h2b, unsigned short* __restrict__ ring,
  const unsigned short* __restrict__ WencP, const unsigned short* __restrict__ W2cP,
  const unsigned short* __restrict__ WhhdP, const unsigned short* __restrict__ WpgP,
  const float* __restrict__ bencP, const float* __restrict__ b2P,
  const float* __restrict__ bd0P, const float* __restrict__ bpg,
  const int* __restrict__ lens, const int* __restrict__ mlen,
  float* __restrict__ outmel, float* __restrict__ outgate)
{
  cg::grid_group grid = cg::this_grid();
  __shared__ float Gs[BB][17];
  __shared__ float cst[BB][4];
  int w = blockIdx.x, tid = threadIdx.x;
  int wv = tid>>6, l = tid&63;

  for(int i=tid;i<BB*4;i+=256) cst[i>>2][i&3]=0.f;
  {
    // zero encoder ping-pong slots 96,97 (32768 uint4)
    uint4* z = (uint4*)(ring + (size_t)96*BB*HH);
    int i = w*256+tid;
    if(i < 32768) z[i] = make_uint4(0,0,0,0);
  }
  grid.sync();

  // ================= encoder: 256 steps, K = 512(x) + 1024(h) =================
  {
    bfv8 bf[48];
    const unsigned short* wp = WencP + (size_t)(w*16 + (l&15))*1536 + (l>>4)*8;
    #pragma unroll
    for(int kt=0;kt<48;kt++) bf[kt] = *(const bfv8*)(const void*)(wp + kt*32);
    const float* bP = bencP + w*16;
    for(int t=0;t<TT;t++){
      const unsigned short* hin  = ring + (size_t)(96 + (t&1))*BB*HH;
      unsigned short* hout = ring + (size_t)(96 + ((t+1)&1))*BB*HH;
      const unsigned short* X = h2b + (size_t)t*BB*EE;
      f32x4 acc0={0,0,0,0}, acc1={0,0,0,0};
      mm_seg<16>(X, EE, bf, acc0, acc1, l, wv);
      mm_seg<32>(hin, HH, bf+16, acc0, acc1, l, wv);
      store_g(acc0, acc1, Gs, l, wv);
      __syncthreads();
      lstm_update(Gs, cst, bP, hin, hout, lens, t, w, tid);
      grid.sync();
    }
  }
  // final encoder h in ring slot 96; c persists in cst

  // ================= decoder: 800 steps, K = 1024 =================
  {
    bfv8 bf[32];
    // step 0: B = Whh_d (sos input is zero), bias = b_d
    {
      const unsigned short* wp = WhhdP + (size_t)(w*16 + (l&15))*HH + (l>>4)*8;
      #pragma unroll
      for(int kt=0;kt<32;kt++) bf[kt] = *(const bfv8*)(const void*)(wp + kt*32);
      const unsigned short* hin = ring + (size_t)96*BB*HH;
      unsigned short* hout = ring;
      f32x4 acc0={0,0,0,0}, acc1={0,0,0,0};
      mm_seg<32>(hin, HH, bf, acc0, acc1, l, wv);
      store_g(acc0, acc1, Gs, l, wv);
      __syncthreads();
      lstm_update(Gs, cst, bd0P + w*16, hin, hout, nullptr, 0, w, tid);
      grid.sync();
    }
    // steps 1..799: B = W2c (mel feedback folded), bias = b2
    {
      const unsigned short* wp = W2cP + (size_t)(w*16 + (l&15))*HH + (l>>4)*8;
      #pragma unroll
      for(int kt=0;kt<32;kt++) bf[kt] = *(const bfv8*)(const void*)(wp + kt*32);
    }
    const float* bP = b2P + w*16;
    for(int t=1;t<TMEL;t++){
      const unsigned short* hin = ring + (size_t)((t-1)%100)*BB*HH;
      unsigned short* hout = ring + (size_t)(t%100)*BB*HH;
      f32x4 acc0={0,0,0,0}, acc1={0,0,0,0};
      mm_seg<32>(hin, HH, bf, acc0, acc1, l, wv);
      store_g(acc0, acc1, Gs, l, wv);
      __syncthreads();
      lstm_update(Gs, cst, bP, hin, hout, nullptr, t, w, tid);
      grid.sync();
      if(t%100==99){
        chunk_proj(ring, WpgP, bpg, mlen, outmel, outgate, t-99, w, l, wv);
        grid.sync();
      }
    }
  }
}

__global__ void k_mask(const int* __restrict__ mlen, float* __restrict__ om){
  int idx=blockIdx.x*256+threadIdx.x; if(idx>=BB*TMEL) return;
  int b=idx/TMEL, t=idx%TMEL;
  om[idx] = (t > mlen[b]) ? 1.f : 0.f;
}

extern "C" void kernel_launch(void* const* d_in, const int* in_sizes, int n_in,
                              void* d_out, int out_size, void* d_ws, size_t ws_size,
                              hipStream_t stream){
  (void)in_sizes; (void)n_in; (void)out_size; (void)ws_size;
  const int*   x    = (const int*)d_in[0];
  const int*   tlen = (const int*)d_in[1];
  const int*   mlen = (const int*)d_in[3];
  const float* emb  = (const float*)d_in[4];
  const float* elW  = (const float*)d_in[5];
  const float* elb  = (const float*)d_in[6];
  const float* c1W  = (const float*)d_in[7];
  const float* c1b  = (const float*)d_in[8];
  const float* g1   = (const float*)d_in[9];
  const float* be1  = (const float*)d_in[10];
  const float* c2W  = (const float*)d_in[11];
  const float* c2b  = (const float*)d_in[12];
  const float* g2   = (const float*)d_in[13];
  const float* be2  = (const float*)d_in[14];
  const float* Wihe = (const float*)d_in[15];
  const float* Whhe = (const float*)d_in[16];
  const float* bhe  = (const float*)d_in[17];
  const float* Wihd = (const float*)d_in[18];
  const float* Whhd = (const float*)d_in[19];
  const float* bhd  = (const float*)d_in[20];
  const float* Wp   = (const float*)d_in[21];
  const float* bp   = (const float*)d_in[22];
  const float* Wg   = (const float*)d_in[23];
  const float* bg   = (const float*)d_in[24];

  float* ws = (float*)d_ws;
  float* proj = ws + OFF_PROJ;
  float* T1   = ws + OFF_T1;
  unsigned short* Wr2b = (unsigned short*)(ws + OFF_WR2);
  float* bb1 = ws + OFF_BB1;
  float* bb2 = ws + OFF_BB2;
  float* b2  = ws + OFF_B2;
  float* W2c = ws + OFF_W2C;
  float* bencP = ws + OFF_BENC;
  float* b2P   = ws + OFF_B2P;
  float* bd0P  = ws + OFF_BD0;
  float* bpg   = ws + OFF_BPG;
  unsigned short* WencP = (unsigned short*)(ws + OFF_WENCP);
  unsigned short* W2cP  = (unsigned short*)(ws + OFF_W2CP);
  unsigned short* WhhdP = (unsigned short*)(ws + OFF_WHHDP);
  unsigned short* WpgP  = (unsigned short*)(ws + OFF_WPGP);
  unsigned short* h2b   = (unsigned short*)(ws + OFF_H2B);
  unsigned short* h1pb  = (unsigned short*)(ws + OFF_H1PB);
  unsigned short* ring  = (unsigned short*)(ws + OFF_H1PB); // alias (h1pb dead after conv2)

  float* outmel  = (float*)d_out;
  float* outgate = outmel + (size_t)BB*TMEL*MELD;
  float* outmask = outgate + (size_t)BB*TMEL;

  k_proj<<<VV,256,0,stream>>>(emb, elW, elb, proj);
  k_t1<<<dim3(VV,3),256,0,stream>>>(proj, c1W, g1, T1);
  k_wr2<<<(EE*3*EE+255)/256,256,0,stream>>>(c2W, g2, Wr2b);
  k_bb<<<2,256,0,stream>>>(c1b,g1,be1,c2b,g2,be2,bb1,bb2);
  k_b2<<<16,256,0,stream>>>(bhd, Wihd, bp, b2);
  k_w2c<<<dim3(G4/8,HH/256),256,0,stream>>>(Whhd, Wihd, Wp, W2c);
  k_pack_enc<<<G4,256,0,stream>>>(Wihe, Whhe, bhe, WencP, bencP);
  k_pack_dec<<<G4,256,0,stream>>>(W2c, Whhd, b2, bhd, W2cP, WhhdP, b2P, bd0P);
  k_pack_pg<<<144,256,0,stream>>>(Wp, Wg, bp, bg, WpgP, bpg);
  k_pad<<<256,256,0,stream>>>(h1pb);
  k_conv1<<<65536,256,0,stream>>>(x, T1, bb1, h1pb);
  k_conv2mm<<<dim3(BB,2,32),256,0,stream>>>(h1pb, Wr2b, bb2, h2b);

  void* kargs[] = {
    (void*)&h2b, (void*)&ring, (void*)&WencP, (void*)&W2cP, (void*)&WhhdP, (void*)&WpgP,
    (void*)&bencP, (void*)&b2P, (void*)&bd0P, (void*)&bpg,
    (void*)&tlen, (void*)&mlen, (void*)&outmel, (void*)&outgate
  };
  hipLaunchCooperativeKernel((void*)k_recur, dim3(256), dim3(256), kargs, 0u, stream);

  k_mask<<<(BB*TMEL+255)/256,256,0,stream>>>(mlen, outmask);
}

// Round 3
// 24038.364 us; speedup vs baseline: 2.8070x; 1.9052x over previous
//
#include <hip/hip_runtime.h>
#include <math.h>

#define BB 128
#define TT 256
#define TMEL 800
#define EE 512
#define HH 1024
#define MELD 128
#define VV 256

// ws offsets (float units)
#define OFF_PROJ  0u
#define OFF_T1    131072u
#define OFF_WR2   524288u
#define OFF_BB1   1310720u
#define OFF_BB2   1311232u
#define OFF_B2    1311744u
#define OFF_W2C   1315840u
#define OFF_BAR   5510144u
#define OFF_WENCR 5522688u
#define OFF_WIHS  7619840u
#define OFF_W2CR  8668416u
#define OFF_WHHDS 10765568u
#define OFF_WPGS  12862720u
#define OFF_H2B   12936448u
#define OFF_RING  21325056u   /* aliases h1pb (dead after conv2) */

typedef __bf16 bfv8 __attribute__((ext_vector_type(8)));
typedef float f32x4 __attribute__((ext_vector_type(4)));

__device__ __forceinline__ unsigned short f2b(float f){
  union { float f; unsigned u; } v; v.f = f;
  unsigned u = v.u;
  return (unsigned short)((u + 0x7fffu + ((u>>16)&1u)) >> 16);
}
__device__ __forceinline__ float sigm(float x){ return 1.0f/(1.0f+expf(-x)); }

__device__ __forceinline__ f32x4 mfma16(bfv8 a, bfv8 b, f32x4 c){
  return __builtin_amdgcn_mfma_f32_16x16x32_bf16(a, b, c, 0, 0, 0);
}

// ---- fp32 precompute kernels (unchanged structure from round 2) ----

__global__ void k_proj(const float* __restrict__ emb, const float* __restrict__ W,
                       const float* __restrict__ bias, float* __restrict__ proj){
  __shared__ float er[EE];
  int v = blockIdx.x;
  for(int i=threadIdx.x;i<EE;i+=256) er[i]=emb[v*EE+i];
  __syncthreads();
  for(int e=threadIdx.x;e<EE;e+=256){
    const float* wr = W + e*EE;
    float acc=0.f;
    for(int k=0;k<EE;k+=4){
      float4 w4 = *(const float4*)(wr+k);
      acc += er[k]*w4.x + er[k+1]*w4.y + er[k+2]*w4.z + er[k+3]*w4.w;
    }
    proj[v*EE+e] = acc + bias[e];
  }
}

__global__ void k_t1(const float* __restrict__ proj, const float* __restrict__ W1,
                     const float* __restrict__ g1, float* __restrict__ T1){
  __shared__ float pr[EE];
  int v = blockIdx.x; int k3 = blockIdx.y;
  for(int i=threadIdx.x;i<EE;i+=256) pr[i]=proj[v*EE+i];
  __syncthreads();
  const float s = rsqrtf(1.f+1e-5f);
  for(int c=threadIdx.x;c<EE;c+=256){
    float acc=0.f;
    const float* w = W1 + c*EE*3 + k3;
    for(int ci=0;ci<EE;ci++) acc += pr[ci]*w[ci*3];
    T1[(v*3+k3)*EE+c] = g1[c]*s*acc;
  }
}

__global__ void k_wr2(const float* __restrict__ W2, const float* __restrict__ g2,
                      unsigned short* __restrict__ Wr){
  int idx = blockIdx.x*256+threadIdx.x;
  if(idx >= EE*3*EE) return;
  int c = idx/1536; int r = idx%1536; int k3 = r/EE; int ci = r%EE;
  const float s = rsqrtf(1.f+1e-5f);
  Wr[idx] = f2b(g2[c]*s*W2[(c*EE+ci)*3+k3]);
}

__global__ void k_bb(const float* __restrict__ b1,const float* __restrict__ g1,const float* __restrict__ be1,
                     const float* __restrict__ b2,const float* __restrict__ g2,const float* __restrict__ be2,
                     float* __restrict__ bb1, float* __restrict__ bb2){
  int c = threadIdx.x + blockIdx.x*256; if(c>=EE) return;
  const float s = rsqrtf(1.f+1e-5f);
  bb1[c] = g1[c]*s*b1[c] + be1[c];
  bb2[c] = g2[c]*s*b2[c] + be2[c];
}

__global__ void k_b2(const float* __restrict__ bd, const float* __restrict__ Wih,
                     const float* __restrict__ bp, float* __restrict__ b2){
  int j = blockIdx.x*256+threadIdx.x; if(j>=4096) return;
  float acc = bd[j];
  const float* w = Wih + j*MELD;
  for(int m=0;m<MELD;m++) acc += w[m]*bp[m];
  b2[j] = acc;
}

__global__ void k_w2c(const float* __restrict__ Whh, const float* __restrict__ Wih,
                      const float* __restrict__ Wp, float* __restrict__ W2c){
  __shared__ float wl[8][MELD];
  int j0 = blockIdx.x*8; int k = blockIdx.y*256 + threadIdx.x;
  for(int i=threadIdx.x;i<8*MELD;i+=256) wl[i/MELD][i%MELD] = Wih[(j0+i/MELD)*MELD + (i%MELD)];
  __syncthreads();
  float acc[8];
  #pragma unroll
  for(int jj=0;jj<8;jj++) acc[jj]=Whh[(j0+jj)*HH+k];
  for(int m=0;m<MELD;m++){
    float wp = Wp[m*HH+k];
    #pragma unroll
    for(int jj=0;jj<8;jj++) acc[jj] += wl[jj][m]*wp;
  }
  #pragma unroll
  for(int jj=0;jj<8;jj++) W2c[(j0+jj)*HH+k] = acc[jj];
}

// ---- fragment packing: tile = cg*8+wv; gate-col j = (wv>>1)*1024 + cg*32 + (wv&1)*16 + (l&15)
//      k = (l>>4)*8 + kt*32 + e ; dst layout [(tile*NKT + kt)*64 + l][8] (lane-major per kt, coalesced)
__global__ void k_pack(const float* __restrict__ src, unsigned short* __restrict__ dst,
                       int NKT, int K){
  int tile = blockIdx.x;
  int cg = tile>>3, wv = tile&7;
  int tot = NKT*64*8;
  for(int i=threadIdx.x; i<tot; i+=256){
    int kt = i>>9; int l = (i>>3)&63; int e = i&7;
    int j = (wv>>1)*1024 + cg*32 + (wv&1)*16 + (l&15);
    int k = ((l>>4)<<3) + kt*32 + e;
    dst[((size_t)(tile*NKT + kt)*64 + l)*8 + e] = f2b(src[(size_t)j*K + k]);
  }
}

__global__ void k_pack_pg(const float* __restrict__ Wp, const float* __restrict__ Wg,
                          unsigned short* __restrict__ dst){
  int nt = blockIdx.x; // 0..8
  for(int i=threadIdx.x; i<32*64*8; i+=256){
    int kt = i>>9; int l = (i>>3)&63; int e = i&7;
    int n = nt*16 + (l&15);
    int k = ((l>>4)<<3) + kt*32 + e;
    float v = (n<MELD)? Wp[(size_t)n*HH+k] : (n==MELD? Wg[k] : 0.f);
    dst[((size_t)(nt*32 + kt)*64 + l)*8 + e] = f2b(v);
  }
}

// ---- conv path ----

__global__ void k_pad(unsigned short* __restrict__ h1pb){
  int idx = blockIdx.x*256+threadIdx.x;
  int c = idx & 511; int b = idx >> 9;
  h1pb[((size_t)b*258)*EE + c] = 0;
  h1pb[((size_t)b*258 + 257)*EE + c] = 0;
}

__global__ void k_conv1(const int* __restrict__ x, const float* __restrict__ T1,
                        const float* __restrict__ bb1, unsigned short* __restrict__ h1pb){
  int idx = blockIdx.x*256+threadIdx.x;
  int c = idx & 511; int bt = idx >> 9; int t = bt & 255; int b = bt >> 8;
  float acc = bb1[c];
  if(t > 0)    acc += T1[(size_t)(x[b*TT+t-1]*3+0)*EE+c];
               acc += T1[(size_t)(x[b*TT+t  ]*3+1)*EE+c];
  if(t < TT-1) acc += T1[(size_t)(x[b*TT+t+1]*3+2)*EE+c];
  h1pb[((size_t)b*258 + t + 1)*EE + c] = f2b(fmaxf(acc, 0.f));
}

// streamed-B MFMA helper (used by conv2)
template<int NKT>
__device__ __forceinline__ void mm_seg_stream(const unsigned short* A, int lda,
    const unsigned short* Wrow, f32x4& acc0, f32x4& acc1, int l, int wv){
  int r0 = wv*32 + (l&15);
  int k8 = (l>>4)*8;
  const unsigned short* a0 = A + (size_t)r0*lda + k8;
  const unsigned short* a1 = a0 + 16*lda;
  const unsigned short* wp = Wrow + k8;
  #pragma unroll
  for(int kt=0;kt<NKT;kt++){
    bfv8 bv = *(const bfv8*)(const void*)(wp + kt*32);
    acc0 = mfma16(*(const bfv8*)(const void*)(a0 + kt*32), bv, acc0);
    acc1 = mfma16(*(const bfv8*)(const void*)(a1 + kt*32), bv, acc1);
  }
}

__global__ __launch_bounds__(256,2) void k_conv2mm(const unsigned short* __restrict__ h1pb,
    const unsigned short* __restrict__ Wr2b, const float* __restrict__ bb2,
    unsigned short* __restrict__ h2b){
  int b = blockIdx.x;    // 0..127
  int th = blockIdx.y;   // 0..1
  int nt = blockIdx.z;   // 0..31
  int tid=threadIdx.x; int wv=tid>>6, l=tid&63;
  const unsigned short* A = h1pb + ((size_t)b*258 + th*128)*EE;
  const unsigned short* Wrow = Wr2b + (size_t)(nt*16+(l&15))*1536;
  f32x4 acc0={0,0,0,0}, acc1={0,0,0,0};
  mm_seg_stream<48>(A, EE, Wrow, acc0, acc1, l, wv);
  int rr=(l>>4)*4, cc=l&15;
  int n = nt*16+cc;
  float bias = bb2[n];
  #pragma unroll
  for(int mi=0;mi<2;mi++){
    f32x4 acc = mi?acc1:acc0;
    int tb = th*128 + wv*32 + mi*16 + rr;
    #pragma unroll
    for(int q=0;q<4;q++){
      float v = fmaxf(acc[q]+bias, 0.f);
      h2b[((size_t)(tb+q)*BB + b)*EE + n] = f2b(v);
    }
  }
}

// ---- group barrier primitives (agent scope, placement-independent) ----
__device__ __forceinline__ void g_arrive(unsigned int* cnt, unsigned int* gen){
  __syncthreads();  // drains each wave's outstanding stores (vmcnt0 before s_barrier)
  if(threadIdx.x == 0){
    unsigned int old = __hip_atomic_fetch_add(cnt, 1u, __ATOMIC_ACQ_REL, __HIP_MEMORY_SCOPE_AGENT);
    if(old == 31u){
      __hip_atomic_store(cnt, 0u, __ATOMIC_RELAXED, __HIP_MEMORY_SCOPE_AGENT);
      __hip_atomic_fetch_add(gen, 1u, __ATOMIC_RELEASE, __HIP_MEMORY_SCOPE_AGENT);
    }
  }
}
__device__ __forceinline__ void g_wait(unsigned int* gen, unsigned int target){
  __syncthreads();
  if(threadIdx.x == 0){
    while(__hip_atomic_load(gen, __ATOMIC_ACQUIRE, __HIP_MEMORY_SCOPE_AGENT) < target)
      __builtin_amdgcn_s_sleep(1);
  }
  __syncthreads();
}

// stage 16 rows x 1024 cols of a ring slot into swizzled LDS (agent loads bypass stale L2)
__device__ __forceinline__ void stage_h(unsigned short* hs, const unsigned short* slotp,
                                        int bg, int tid){
  for(int i = tid; i < 4096; i += 512){
    int r = i >> 8, c8 = i & 255;
    const unsigned long long* p =
      (const unsigned long long*)(slotp + (size_t)(bg*16+r)*HH + c8*4);
    unsigned long long v = __hip_atomic_load(p, __ATOMIC_RELAXED, __HIP_MEMORY_SCOPE_AGENT);
    *(unsigned long long*)((char*)hs + ((r*2048 + c8*8) ^ ((r&7)<<4))) = v;
  }
}

// ---- the persistent recurrence kernel: 256 WGs = 32 col-groups x 8 batch-groups ----
__global__ __launch_bounds__(512,2) void k_recur(
  const unsigned short* __restrict__ h2b, unsigned short* __restrict__ ring,
  const unsigned short* __restrict__ WencR, const unsigned short* __restrict__ WihS,
  const unsigned short* __restrict__ W2cR, const unsigned short* __restrict__ WhhdS,
  const unsigned short* __restrict__ WpgS,
  const float* __restrict__ bhe, const float* __restrict__ bd, const float* __restrict__ b2,
  const float* __restrict__ bp, const float* __restrict__ bgp,
  unsigned int* __restrict__ bar,
  const int* __restrict__ tlen, const int* __restrict__ mlen,
  float* __restrict__ outmel, float* __restrict__ outgate)
{
  __shared__ __align__(16) unsigned short hs[16*1024];  // 32KB
  __shared__ __align__(16) unsigned short Xs[16*512];   // 16KB
  __shared__ float Gs[16][132];

  const int bid = blockIdx.x;
  const int bg = bid & 7, cg = bid >> 3;   // bid%8 -> same-XCD group under round-robin (perf only)
  const int tid = threadIdx.x;
  const int wvi = tid >> 6, l = tid & 63;
  const int tile = cg*8 + wvi;
  unsigned int* cnt = bar + bg*32;
  unsigned int* gen = bar + 256 + bg*32;
  unsigned int ge = 1;

  const int fr = l & 15;
  const int hswz = (fr & 7) << 4;
  const int hbase = fr*2048 + ((l>>4)<<4);
  const int xbase = fr*1024 + ((l>>4)<<4);

  // lstm-thread constants (tid<256): row lr (0..15), col pair lc within group stripe
  const int lr = tid >> 4;
  const int lc = (tid & 15) * 2;
  const int hcol = cg*32 + lc;
  float cs0 = 0.f, cs1 = 0.f;
  unsigned int hp = 0u;
  int mylen = 0;
  if(tid < 256) mylen = tlen[bg*16 + lr];

  // zero enc h_0 (slot 100): WG stripe rows bg*16..+16, cols cg*32..+32
  if(tid < 128){
    int r = tid >> 3, c4 = (tid & 7) * 4;
    unsigned long long* p = (unsigned long long*)
      (ring + (size_t)100*BB*HH + (size_t)(bg*16+r)*HH + cg*32 + c4);
    __hip_atomic_store(p, 0ull, __ATOMIC_RELAXED, __HIP_MEMORY_SCOPE_AGENT);
  }
  g_arrive(cnt, gen);   // gen -> 1 when group done

  bfv8 bf[32];

  // ================= encoder: 256 steps =================
  #pragma unroll 1
  for(int kt=0;kt<32;kt++)
    bf[kt] = *(const bfv8*)(const void*)(WencR + ((size_t)(tile*32+kt)*64 + l)*8);

  #pragma unroll 1
  for(int t=0;t<TT;t++){
    // stage X_t (precomputed, normal loads, L2-hot)
    {
      const uint4* src = (const uint4*)(h2b + (size_t)(t*BB + bg*16)*EE);
      for(int i = tid; i < 1024; i += 512){
        int r = i >> 6, c16 = i & 63;
        uint4 v = src[r*64 + c16];
        *(uint4*)((char*)Xs + ((r*1024 + c16*16) ^ ((r&7)<<4))) = v;
      }
    }
    __syncthreads();
    // accPre = Wih . x_t  (streamed B, overlaps with barrier wait below)
    f32x4 acc = {0.f,0.f,0.f,0.f};
    {
      const unsigned short* wsrc = WihS + (size_t)tile*16*64*8;
      #pragma unroll
      for(int kt=0;kt<16;kt++){
        bfv8 wf = *(const bfv8*)(const void*)(wsrc + ((size_t)kt*64 + l)*8);
        bfv8 xv = *(const bfv8*)(const void*)((const char*)Xs + ((xbase + kt*64) ^ hswz));
        acc = mfma16(xv, wf, acc);
      }
    }
    g_wait(gen, ge);   // h_t ready
    stage_h(hs, ring + (size_t)(100 + (t&1))*BB*HH, bg, tid);
    __syncthreads();
    #pragma unroll
    for(int kt=0;kt<32;kt++){
      bfv8 hv = *(const bfv8*)(const void*)((const char*)hs + ((hbase + kt*64) ^ hswz));
      acc = mfma16(hv, bf[kt], acc);
    }
    {
      int rr = (l>>4)*4;
      #pragma unroll
      for(int q=0;q<4;q++) Gs[rr+q][wvi*16 + fr] = acc[q];
    }
    __syncthreads();
    if(tid < 256){
      float gi0 = Gs[lr][lc]      + bhe[hcol],        gi1 = Gs[lr][lc+1]    + bhe[hcol+1];
      float gf0 = Gs[lr][32+lc]   + bhe[HH+hcol],     gf1 = Gs[lr][33+lc]   + bhe[HH+hcol+1];
      float gg0 = Gs[lr][64+lc]   + bhe[2*HH+hcol],   gg1 = Gs[lr][65+lc]   + bhe[2*HH+hcol+1];
      float go0 = Gs[lr][96+lc]   + bhe[3*HH+hcol],   go1 = Gs[lr][97+lc]   + bhe[3*HH+hcol+1];
      float c20 = sigm(gf0)*cs0 + sigm(gi0)*tanhf(gg0);
      float c21 = sigm(gf1)*cs1 + sigm(gi1)*tanhf(gg1);
      float h20 = sigm(go0)*tanhf(c20);
      float h21 = sigm(go1)*tanhf(c21);
      if(t < mylen){
        cs0 = c20; cs1 = c21;
        hp = (unsigned)f2b(h20) | ((unsigned)f2b(h21)<<16);
      }
      unsigned short* outslot = (t==TT-1) ? (ring + (size_t)99*BB*HH)
                                          : (ring + (size_t)(100 + ((t+1)&1))*BB*HH);
      __hip_atomic_store((unsigned int*)(outslot + (size_t)(bg*16+lr)*HH + hcol), hp,
                         __ATOMIC_RELAXED, __HIP_MEMORY_SCOPE_AGENT);
    }
    g_arrive(cnt, gen); ge++;
  }

  // ================= decoder: 800 steps =================
  #pragma unroll 1
  for(int kt=0;kt<32;kt++)
    bf[kt] = *(const bfv8*)(const void*)(W2cR + ((size_t)(tile*32+kt)*64 + l)*8);

  #pragma unroll 1
  for(int t=0;t<TMEL;t++){
    g_wait(gen, ge);   // s_t ready
    const unsigned short* slotin = (t==0) ? ring + (size_t)99*BB*HH
                                          : ring + (size_t)((t-1)%100)*BB*HH;
    stage_h(hs, slotin, bg, tid);
    __syncthreads();
    f32x4 acc = {0.f,0.f,0.f,0.f};
    if(t == 0){
      const unsigned short* wsrc = WhhdS + (size_t)tile*32*64*8;
      #pragma unroll
      for(int kt=0;kt<32;kt++){
        bfv8 wf = *(const bfv8*)(const void*)(wsrc + ((size_t)kt*64 + l)*8);
        bfv8 hv = *(const bfv8*)(const void*)((const char*)hs + ((hbase + kt*64) ^ hswz));
        acc = mfma16(hv, wf, acc);
      }
    } else {
      #pragma unroll
      for(int kt=0;kt<32;kt++){
        bfv8 hv = *(const bfv8*)(const void*)((const char*)hs + ((hbase + kt*64) ^ hswz));
        acc = mfma16(hv, bf[kt], acc);
      }
    }
    {
      int rr = (l>>4)*4;
      #pragma unroll
      for(int q=0;q<4;q++) Gs[rr+q][wvi*16 + fr] = acc[q];
    }
    __syncthreads();
    if(tid < 256){
      const float* bs = (t==0) ? bd : b2;
      float gi0 = Gs[lr][lc]      + bs[hcol],        gi1 = Gs[lr][lc+1]    + bs[hcol+1];
      float gf0 = Gs[lr][32+lc]   + bs[HH+hcol],     gf1 = Gs[lr][33+lc]   + bs[HH+hcol+1];
      float gg0 = Gs[lr][64+lc]   + bs[2*HH+hcol],   gg1 = Gs[lr][65+lc]   + bs[2*HH+hcol+1];
      float go0 = Gs[lr][96+lc]   + bs[3*HH+hcol],   go1 = Gs[lr][97+lc]   + bs[3*HH+hcol+1];
      float c20 = sigm(gf0)*cs0 + sigm(gi0)*tanhf(gg0);
      float c21 = sigm(gf1)*cs1 + sigm(gi1)*tanhf(gg1);
      cs0 = c20; cs1 = c21;
      float h20 = sigm(go0)*tanhf(c20);
      float h21 = sigm(go1)*tanhf(c21);
      unsigned int hn = (unsigned)f2b(h20) | ((unsigned)f2b(h21)<<16);
      unsigned short* outslot = ring + (size_t)(t%100)*BB*HH;
      __hip_atomic_store((unsigned int*)(outslot + (size_t)(bg*16+lr)*HH + hcol), hn,
                         __ATOMIC_RELAXED, __HIP_MEMORY_SCOPE_AGENT);
    }
    g_arrive(cnt, gen); ge++;

    if((t%100)==99){
      g_wait(gen, ge);   // all 100 slots final
      int tbase = t - 99;
      #pragma unroll 1
      for(int s = cg; s < 100; s += 32){
        stage_h(hs, ring + (size_t)s*BB*HH, bg, tid);
        __syncthreads();
        int tout = tbase + s;
        #pragma unroll 1
        for(int pass=0; pass<2; pass++){
          int nt = (pass==0) ? wvi : 8;
          if(pass==1 && wvi!=0) break;
          const unsigned short* wsrc = WpgS + (size_t)nt*32*64*8;
          f32x4 acc = {0.f,0.f,0.f,0.f};
          #pragma unroll
          for(int kt=0;kt<32;kt++){
            bfv8 wf = *(const bfv8*)(const void*)(wsrc + ((size_t)kt*64 + l)*8);
            bfv8 hv = *(const bfv8*)(const void*)((const char*)hs + ((hbase + kt*64) ^ hswz));
            acc = mfma16(hv, wf, acc);
          }
          int n = nt*16 + fr;
          #pragma unroll
          for(int q=0;q<4;q++){
            int b = bg*16 + (l>>4)*4 + q;
            bool msk = tout > mlen[b];
            if(n < MELD)
              outmel[((size_t)b*TMEL + tout)*MELD + n] = msk ? 0.f : acc[q]+bp[n];
            else if(n == MELD)
              outgate[(size_t)b*TMEL + tout] = msk ? 1000.f : acc[q]+bgp[0];
          }
        }
        __syncthreads();
      }
      g_arrive(cnt, gen); ge++;
    }
  }
}

__global__ void k_mask(const int* __restrict__ mlen, float* __restrict__ om){
  int idx=blockIdx.x*256+threadIdx.x; if(idx>=BB*TMEL) return;
  int b=idx/TMEL, t=idx%TMEL;
  om[idx] = (t > mlen[b]) ? 1.f : 0.f;
}

extern "C" void kernel_launch(void* const* d_in, const int* in_sizes, int n_in,
                              void* d_out, int out_size, void* d_ws, size_t ws_size,
                              hipStream_t stream){
  (void)in_sizes; (void)n_in; (void)out_size; (void)ws_size;
  const int*   x    = (const int*)d_in[0];
  const int*   tlen = (const int*)d_in[1];
  const int*   mlen = (const int*)d_in[3];
  const float* emb  = (const float*)d_in[4];
  const float* elW  = (const float*)d_in[5];
  const float* elb  = (const float*)d_in[6];
  const float* c1W  = (const float*)d_in[7];
  const float* c1b  = (const float*)d_in[8];
  const float* g1   = (const float*)d_in[9];
  const float* be1  = (const float*)d_in[10];
  const float* c2W  = (const float*)d_in[11];
  const float* c2b  = (const float*)d_in[12];
  const float* g2   = (const float*)d_in[13];
  const float* be2  = (const float*)d_in[14];
  const float* Wihe = (const float*)d_in[15];
  const float* Whhe = (const float*)d_in[16];
  const float* bhe  = (const float*)d_in[17];
  const float* Wihd = (const float*)d_in[18];
  const float* Whhd = (const float*)d_in[19];
  const float* bhd  = (const float*)d_in[20];
  const float* Wp   = (const float*)d_in[21];
  const float* bp   = (const float*)d_in[22];
  const float* Wg   = (const float*)d_in[23];
  const float* bg   = (const float*)d_in[24];

  float* ws = (float*)d_ws;
  float* proj = ws + OFF_PROJ;
  float* T1   = ws + OFF_T1;
  unsigned short* Wr2b = (unsigned short*)(ws + OFF_WR2);
  float* bb1 = ws + OFF_BB1;
  float* bb2 = ws + OFF_BB2;
  float* b2  = ws + OFF_B2;
  float* W2c = ws + OFF_W2C;
  unsigned int* bar = (unsigned int*)(ws + OFF_BAR);
  unsigned short* WencR = (unsigned short*)(ws + OFF_WENCR);
  unsigned short* WihS  = (unsigned short*)(ws + OFF_WIHS);
  unsigned short* W2cR  = (unsigned short*)(ws + OFF_W2CR);
  unsigned short* WhhdS = (unsigned short*)(ws + OFF_WHHDS);
  unsigned short* WpgS  = (unsigned short*)(ws + OFF_WPGS);
  unsigned short* h2b   = (unsigned short*)(ws + OFF_H2B);
  unsigned short* h1pb  = (unsigned short*)(ws + OFF_RING); // conv scratch
  unsigned short* ring  = (unsigned short*)(ws + OFF_RING); // alias after conv2

  float* outmel  = (float*)d_out;
  float* outgate = outmel + (size_t)BB*TMEL*MELD;
  float* outmask = outgate + (size_t)BB*TMEL;

  hipMemsetAsync(bar, 0, 2048, stream);

  k_proj<<<VV,256,0,stream>>>(emb, elW, elb, proj);
  k_t1<<<dim3(VV,3),256,0,stream>>>(proj, c1W, g1, T1);
  k_wr2<<<(EE*3*EE+255)/256,256,0,stream>>>(c2W, g2, Wr2b);
  k_bb<<<2,256,0,stream>>>(c1b,g1,be1,c2b,g2,be2,bb1,bb2);
  k_b2<<<16,256,0,stream>>>(bhd, Wihd, bp, b2);
  k_w2c<<<dim3(4096/8,HH/256),256,0,stream>>>(Whhd, Wihd, Wp, W2c);
  k_pack<<<256,256,0,stream>>>(Whhe, WencR, 32, 1024);
  k_pack<<<256,256,0,stream>>>(Wihe, WihS, 16, 512);
  k_pack<<<256,256,0,stream>>>(W2c,  W2cR, 32, 1024);
  k_pack<<<256,256,0,stream>>>(Whhd, WhhdS, 32, 1024);
  k_pack_pg<<<9,256,0,stream>>>(Wp, Wg, WpgS);
  k_pad<<<256,256,0,stream>>>(h1pb);
  k_conv1<<<65536,256,0,stream>>>(x, T1, bb1, h1pb);
  k_conv2mm<<<dim3(BB,2,32),256,0,stream>>>(h1pb, Wr2b, bb2, h2b);

  void* kargs[] = {
    (void*)&h2b, (void*)&ring, (void*)&WencR, (void*)&WihS, (void*)&W2cR, (void*)&WhhdS,
    (void*)&WpgS, (void*)&bhe, (void*)&bhd, (void*)&b2, (void*)&bp, (void*)&bg,
    (void*)&bar, (void*)&tlen, (void*)&mlen, (void*)&outmel, (void*)&outgate
  };
  hipLaunchCooperativeKernel((void*)k_recur, dim3(256), dim3(512), kargs, 0u, stream);

  k_mask<<<(BB*TMEL+255)/256,256,0,stream>>>(mlen, outmask);
}

// Round 4
// 14105.064 us; speedup vs baseline: 4.7837x; 1.7042x over previous
//
#include <hip/hip_runtime.h>
#include <math.h>

#define BB 128
#define TT 256
#define TMEL 800
#define EE 512
#define HH 1024
#define MELD 128
#define VV 256

// ws offsets (float units)
#define OFF_PROJ  0u
#define OFF_T1    131072u
#define OFF_WR2   524288u
#define OFF_BB1   1310720u
#define OFF_BB2   1311232u
#define OFF_B2    1311744u
#define OFF_W2C   1315840u
#define OFF_BAR   5510144u
#define OFF_WENCR 5522688u
#define OFF_WIHS  7619840u
#define OFF_W2CR  8668416u
#define OFF_WHHDS 10765568u
#define OFF_WPGS  12862720u
#define OFF_H2B   12936448u
#define OFF_RING  21325056u   /* aliases h1pb (dead after conv2) */

typedef __bf16 bfv8 __attribute__((ext_vector_type(8)));
typedef float f32x4 __attribute__((ext_vector_type(4)));

__device__ __forceinline__ unsigned short f2b(float f){
  union { float f; unsigned u; } v; v.f = f;
  unsigned u = v.u;
  return (unsigned short)((u + 0x7fffu + ((u>>16)&1u)) >> 16);
}
__device__ __forceinline__ float sigm(float x){ return 1.0f/(1.0f+expf(-x)); }

__device__ __forceinline__ f32x4 mfma16(bfv8 a, bfv8 b, f32x4 c){
  return __builtin_amdgcn_mfma_f32_16x16x32_bf16(a, b, c, 0, 0, 0);
}

// ---- fp32 precompute kernels ----

__global__ void k_proj(const float* __restrict__ emb, const float* __restrict__ W,
                       const float* __restrict__ bias, float* __restrict__ proj){
  __shared__ float er[EE];
  int v = blockIdx.x;
  for(int i=threadIdx.x;i<EE;i+=256) er[i]=emb[v*EE+i];
  __syncthreads();
  for(int e=threadIdx.x;e<EE;e+=256){
    const float* wr = W + e*EE;
    float acc=0.f;
    for(int k=0;k<EE;k+=4){
      float4 w4 = *(const float4*)(wr+k);
      acc += er[k]*w4.x + er[k+1]*w4.y + er[k+2]*w4.z + er[k+3]*w4.w;
    }
    proj[v*EE+e] = acc + bias[e];
  }
}

__global__ void k_t1(const float* __restrict__ proj, const float* __restrict__ W1,
                     const float* __restrict__ g1, float* __restrict__ T1){
  __shared__ float pr[EE];
  int v = blockIdx.x; int k3 = blockIdx.y;
  for(int i=threadIdx.x;i<EE;i+=256) pr[i]=proj[v*EE+i];
  __syncthreads();
  const float s = rsqrtf(1.f+1e-5f);
  for(int c=threadIdx.x;c<EE;c+=256){
    float acc=0.f;
    const float* w = W1 + c*EE*3 + k3;
    for(int ci=0;ci<EE;ci++) acc += pr[ci]*w[ci*3];
    T1[(v*3+k3)*EE+c] = g1[c]*s*acc;
  }
}

__global__ void k_wr2(const float* __restrict__ W2, const float* __restrict__ g2,
                      unsigned short* __restrict__ Wr){
  int idx = blockIdx.x*256+threadIdx.x;
  if(idx >= EE*3*EE) return;
  int c = idx/1536; int r = idx%1536; int k3 = r/EE; int ci = r%EE;
  const float s = rsqrtf(1.f+1e-5f);
  Wr[idx] = f2b(g2[c]*s*W2[(c*EE+ci)*3+k3]);
}

__global__ void k_bb(const float* __restrict__ b1,const float* __restrict__ g1,const float* __restrict__ be1,
                     const float* __restrict__ b2,const float* __restrict__ g2,const float* __restrict__ be2,
                     float* __restrict__ bb1, float* __restrict__ bb2){
  int c = threadIdx.x + blockIdx.x*256; if(c>=EE) return;
  const float s = rsqrtf(1.f+1e-5f);
  bb1[c] = g1[c]*s*b1[c] + be1[c];
  bb2[c] = g2[c]*s*b2[c] + be2[c];
}

__global__ void k_b2(const float* __restrict__ bd, const float* __restrict__ Wih,
                     const float* __restrict__ bp, float* __restrict__ b2){
  int j = blockIdx.x*256+threadIdx.x; if(j>=4096) return;
  float acc = bd[j];
  const float* w = Wih + j*MELD;
  for(int m=0;m<MELD;m++) acc += w[m]*bp[m];
  b2[j] = acc;
}

__global__ void k_w2c(const float* __restrict__ Whh, const float* __restrict__ Wih,
                      const float* __restrict__ Wp, float* __restrict__ W2c){
  __shared__ float wl[8][MELD];
  int j0 = blockIdx.x*8; int k = blockIdx.y*256 + threadIdx.x;
  for(int i=threadIdx.x;i<8*MELD;i+=256) wl[i/MELD][i%MELD] = Wih[(j0+i/MELD)*MELD + (i%MELD)];
  __syncthreads();
  float acc[8];
  #pragma unroll
  for(int jj=0;jj<8;jj++) acc[jj]=Whh[(j0+jj)*HH+k];
  for(int m=0;m<MELD;m++){
    float wp = Wp[m*HH+k];
    #pragma unroll
    for(int jj=0;jj<8;jj++) acc[jj] += wl[jj][m]*wp;
  }
  #pragma unroll
  for(int jj=0;jj<8;jj++) W2c[(j0+jj)*HH+k] = acc[jj];
}

// ---- fragment packing ----
__global__ void k_pack(const float* __restrict__ src, unsigned short* __restrict__ dst,
                       int NKT, int K){
  int tile = blockIdx.x;
  int cg = tile>>3, wv = tile&7;
  int tot = NKT*64*8;
  for(int i=threadIdx.x; i<tot; i+=256){
    int kt = i>>9; int l = (i>>3)&63; int e = i&7;
    int j = (wv>>1)*1024 + cg*32 + (wv&1)*16 + (l&15);
    int k = ((l>>4)<<3) + kt*32 + e;
    dst[((size_t)(tile*NKT + kt)*64 + l)*8 + e] = f2b(src[(size_t)j*K + k]);
  }
}

__global__ void k_pack_pg(const float* __restrict__ Wp, const float* __restrict__ Wg,
                          unsigned short* __restrict__ dst){
  int nt = blockIdx.x; // 0..8
  for(int i=threadIdx.x; i<32*64*8; i+=256){
    int kt = i>>9; int l = (i>>3)&63; int e = i&7;
    int n = nt*16 + (l&15);
    int k = ((l>>4)<<3) + kt*32 + e;
    float v = (n<MELD)? Wp[(size_t)n*HH+k] : (n==MELD? Wg[k] : 0.f);
    dst[((size_t)(nt*32 + kt)*64 + l)*8 + e] = f2b(v);
  }
}

// ---- conv path ----

__global__ void k_pad(unsigned short* __restrict__ h1pb){
  int idx = blockIdx.x*256+threadIdx.x;
  int c = idx & 511; int b = idx >> 9;
  h1pb[((size_t)b*258)*EE + c] = 0;
  h1pb[((size_t)b*258 + 257)*EE + c] = 0;
}

__global__ void k_conv1(const int* __restrict__ x, const float* __restrict__ T1,
                        const float* __restrict__ bb1, unsigned short* __restrict__ h1pb){
  int idx = blockIdx.x*256+threadIdx.x;
  int c = idx & 511; int bt = idx >> 9; int t = bt & 255; int b = bt >> 8;
  float acc = bb1[c];
  if(t > 0)    acc += T1[(size_t)(x[b*TT+t-1]*3+0)*EE+c];
               acc += T1[(size_t)(x[b*TT+t  ]*3+1)*EE+c];
  if(t < TT-1) acc += T1[(size_t)(x[b*TT+t+1]*3+2)*EE+c];
  h1pb[((size_t)b*258 + t + 1)*EE + c] = f2b(fmaxf(acc, 0.f));
}

template<int NKT>
__device__ __forceinline__ void mm_seg_stream(const unsigned short* A, int lda,
    const unsigned short* Wrow, f32x4& acc0, f32x4& acc1, int l, int wv){
  int r0 = wv*32 + (l&15);
  int k8 = (l>>4)*8;
  const unsigned short* a0 = A + (size_t)r0*lda + k8;
  const unsigned short* a1 = a0 + 16*lda;
  const unsigned short* wp = Wrow + k8;
  #pragma unroll
  for(int kt=0;kt<NKT;kt++){
    bfv8 bv = *(const bfv8*)(const void*)(wp + kt*32);
    acc0 = mfma16(*(const bfv8*)(const void*)(a0 + kt*32), bv, acc0);
    acc1 = mfma16(*(const bfv8*)(const void*)(a1 + kt*32), bv, acc1);
  }
}

__global__ __launch_bounds__(256,2) void k_conv2mm(const unsigned short* __restrict__ h1pb,
    const unsigned short* __restrict__ Wr2b, const float* __restrict__ bb2,
    unsigned short* __restrict__ h2b){
  int b = blockIdx.x;    // 0..127
  int th = blockIdx.y;   // 0..1
  int nt = blockIdx.z;   // 0..31
  int tid=threadIdx.x; int wv=tid>>6, l=tid&63;
  const unsigned short* A = h1pb + ((size_t)b*258 + th*128)*EE;
  const unsigned short* Wrow = Wr2b + (size_t)(nt*16+(l&15))*1536;
  f32x4 acc0={0,0,0,0}, acc1={0,0,0,0};
  mm_seg_stream<48>(A, EE, Wrow, acc0, acc1, l, wv);
  int rr=(l>>4)*4, cc=l&15;
  int n = nt*16+cc;
  float bias = bb2[n];
  #pragma unroll
  for(int mi=0;mi<2;mi++){
    f32x4 acc = mi?acc1:acc0;
    int tb = th*128 + wv*32 + mi*16 + rr;
    #pragma unroll
    for(int q=0;q<4;q++){
      float v = fmaxf(acc[q]+bias, 0.f);
      h2b[((size_t)(tb+q)*BB + b)*EE + n] = f2b(v);
    }
  }
}

// ---- group barrier: ALL RELAXED (no buffer_inv/wbl2 on the critical path).
// Ordering: h-stores are relaxed agent-scope atomics (complete at the device
// coherence point); __syncthreads() drains vmcnt(0) per wave BEFORE s_barrier,
// so stores are acked before thread0 issues the relaxed fetch_add. A consumer
// observing gen therefore observes all h-stores via its own relaxed atomic loads.
__device__ __forceinline__ void g_arrive(unsigned int* cnt, unsigned int* gen){
  __syncthreads();  // vmcnt(0) drain: h-stores acked at coherence point
  if(threadIdx.x == 0){
    unsigned int old = __hip_atomic_fetch_add(cnt, 1u, __ATOMIC_RELAXED, __HIP_MEMORY_SCOPE_AGENT);
    if(old == 31u){
      __hip_atomic_store(cnt, 0u, __ATOMIC_RELAXED, __HIP_MEMORY_SCOPE_AGENT);
      __hip_atomic_fetch_add(gen, 1u, __ATOMIC_RELAXED, __HIP_MEMORY_SCOPE_AGENT);
    }
  }
}
__device__ __forceinline__ void g_wait(unsigned int* gen, unsigned int target){
  if(threadIdx.x == 0){
    while(__hip_atomic_load(gen, __ATOMIC_RELAXED, __HIP_MEMORY_SCOPE_AGENT) < target)
      __builtin_amdgcn_s_sleep(1);
  }
  asm volatile("" ::: "memory");
  __syncthreads();
}

// stage 16 rows x 1024 cols of a ring slot into swizzled LDS
__device__ __forceinline__ void stage_h(unsigned short* hs, const unsigned short* slotp,
                                        int bg, int tid){
  for(int i = tid; i < 4096; i += 512){
    int r = i >> 8, c8 = i & 255;
    const unsigned long long* p =
      (const unsigned long long*)(slotp + (size_t)(bg*16+r)*HH + c8*4);
    unsigned long long v = __hip_atomic_load(p, __ATOMIC_RELAXED, __HIP_MEMORY_SCOPE_AGENT);
    *(unsigned long long*)((char*)hs + ((r*2048 + c8*8) ^ ((r&7)<<4))) = v;
  }
}

// ---- persistent recurrence: 256 WGs = 32 col-groups x 8 batch-groups ----
__global__ __launch_bounds__(512,2) void k_recur(
  const unsigned short* __restrict__ h2b, unsigned short* __restrict__ ring,
  const unsigned short* __restrict__ WencR, const unsigned short* __restrict__ WihS,
  const unsigned short* __restrict__ W2cR, const unsigned short* __restrict__ WhhdS,
  const unsigned short* __restrict__ WpgS,
  const float* __restrict__ bhe, const float* __restrict__ bd, const float* __restrict__ b2,
  const float* __restrict__ bp, const float* __restrict__ bgp,
  unsigned int* __restrict__ bar,
  const int* __restrict__ tlen, const int* __restrict__ mlen,
  float* __restrict__ outmel, float* __restrict__ outgate)
{
  __shared__ __align__(16) unsigned short hs[16*1024];  // 32KB
  __shared__ __align__(16) unsigned short Xs[16*512];   // 16KB
  __shared__ float Gs[16][132];

  const int bid = blockIdx.x;
  const int bg = bid & 7, cg = bid >> 3;
  const int tid = threadIdx.x;
  const int wvi = tid >> 6, l = tid & 63;
  const int tile = cg*8 + wvi;
  unsigned int* cnt = bar + bg*32;
  unsigned int* gen = bar + 256 + bg*32;
  unsigned int ge = 1;

  const int fr = l & 15;
  const int hswz = (fr & 7) << 4;
  const int hbase = fr*2048 + ((l>>4)<<4);
  const int xbase = fr*1024 + ((l>>4)<<4);

  const int lr = tid >> 4;
  const int lc = (tid & 15) * 2;
  const int hcol = cg*32 + lc;
  float cs0 = 0.f, cs1 = 0.f;
  unsigned int hp = 0u;
  int mylen = 0;
  if(tid < 256) mylen = tlen[bg*16 + lr];

  // zero enc h_0 (slot 100)
  if(tid < 128){
    int r = tid >> 3, c4 = (tid & 7) * 4;
    unsigned long long* p = (unsigned long long*)
      (ring + (size_t)100*BB*HH + (size_t)(bg*16+r)*HH + cg*32 + c4);
    __hip_atomic_store(p, 0ull, __ATOMIC_RELAXED, __HIP_MEMORY_SCOPE_AGENT);
  }
  g_arrive(cnt, gen);

  bfv8 bf[32];

  // ================= encoder: 256 steps =================
  #pragma unroll 1
  for(int kt=0;kt<32;kt++)
    bf[kt] = *(const bfv8*)(const void*)(WencR + ((size_t)(tile*32+kt)*64 + l)*8);

  // bias preload (loop-invariant)
  float ei0=0,ei1=0,ef0=0,ef1=0,eg0=0,eg1=0,eo0=0,eo1=0;
  if(tid < 256){
    ei0=bhe[hcol];      ei1=bhe[hcol+1];
    ef0=bhe[HH+hcol];   ef1=bhe[HH+hcol+1];
    eg0=bhe[2*HH+hcol]; eg1=bhe[2*HH+hcol+1];
    eo0=bhe[3*HH+hcol]; eo1=bhe[3*HH+hcol+1];
  }

  #pragma unroll 1
  for(int t=0;t<TT;t++){
    {
      const uint4* src = (const uint4*)(h2b + (size_t)(t*BB + bg*16)*EE);
      for(int i = tid; i < 1024; i += 512){
        int r = i >> 6, c16 = i & 63;
        uint4 v = src[r*64 + c16];
        *(uint4*)((char*)Xs + ((r*1024 + c16*16) ^ ((r&7)<<4))) = v;
      }
    }
    __syncthreads();
    f32x4 acc = {0.f,0.f,0.f,0.f};
    {
      const unsigned short* wsrc = WihS + (size_t)tile*16*64*8;
      #pragma unroll
      for(int kt=0;kt<16;kt++){
        bfv8 wf = *(const bfv8*)(const void*)(wsrc + ((size_t)kt*64 + l)*8);
        bfv8 xv = *(const bfv8*)(const void*)((const char*)Xs + ((xbase + kt*64) ^ hswz));
        acc = mfma16(xv, wf, acc);
      }
    }
    g_wait(gen, ge);   // h_t ready
    stage_h(hs, ring + (size_t)(100 + (t&1))*BB*HH, bg, tid);
    __syncthreads();
    #pragma unroll
    for(int kt=0;kt<32;kt++){
      bfv8 hv = *(const bfv8*)(const void*)((const char*)hs + ((hbase + kt*64) ^ hswz));
      acc = mfma16(hv, bf[kt], acc);
    }
    {
      int rr = (l>>4)*4;
      #pragma unroll
      for(int q=0;q<4;q++) Gs[rr+q][wvi*16 + fr] = acc[q];
    }
    __syncthreads();
    if(tid < 256){
      float gi0 = Gs[lr][lc]    + ei0, gi1 = Gs[lr][lc+1] + ei1;
      float gf0 = Gs[lr][32+lc] + ef0, gf1 = Gs[lr][33+lc] + ef1;
      float gg0 = Gs[lr][64+lc] + eg0, gg1 = Gs[lr][65+lc] + eg1;
      float go0 = Gs[lr][96+lc] + eo0, go1 = Gs[lr][97+lc] + eo1;
      float c20 = sigm(gf0)*cs0 + sigm(gi0)*tanhf(gg0);
      float c21 = sigm(gf1)*cs1 + sigm(gi1)*tanhf(gg1);
      float h20 = sigm(go0)*tanhf(c20);
      float h21 = sigm(go1)*tanhf(c21);
      if(t < mylen){
        cs0 = c20; cs1 = c21;
        hp = (unsigned)f2b(h20) | ((unsigned)f2b(h21)<<16);
      }
      unsigned short* outslot = (t==TT-1) ? (ring + (size_t)99*BB*HH)
                                          : (ring + (size_t)(100 + ((t+1)&1))*BB*HH);
      __hip_atomic_store((unsigned int*)(outslot + (size_t)(bg*16+lr)*HH + hcol), hp,
                         __ATOMIC_RELAXED, __HIP_MEMORY_SCOPE_AGENT);
    }
    g_arrive(cnt, gen); ge++;
  }

  // ================= decoder: 800 steps =================
  #pragma unroll 1
  for(int kt=0;kt<32;kt++)
    bf[kt] = *(const bfv8*)(const void*)(W2cR + ((size_t)(tile*32+kt)*64 + l)*8);

  float di0=0,di1=0,df0=0,df1=0,dg0=0,dg1=0,do0=0,do1=0;
  if(tid < 256){
    di0=b2[hcol];      di1=b2[hcol+1];
    df0=b2[HH+hcol];   df1=b2[HH+hcol+1];
    dg0=b2[2*HH+hcol]; dg1=b2[2*HH+hcol+1];
    do0=b2[3*HH+hcol]; do1=b2[3*HH+hcol+1];
  }

  #pragma unroll 1
  for(int t=0;t<TMEL;t++){
    g_wait(gen, ge);   // s_t ready
    const unsigned short* slotin = (t==0) ? ring + (size_t)99*BB*HH
                                          : ring + (size_t)((t-1)%100)*BB*HH;
    stage_h(hs, slotin, bg, tid);
    __syncthreads();
    f32x4 acc = {0.f,0.f,0.f,0.f};
    if(t == 0){
      const unsigned short* wsrc = WhhdS + (size_t)tile*32*64*8;
      #pragma unroll
      for(int kt=0;kt<32;kt++){
        bfv8 wf = *(const bfv8*)(const void*)(wsrc + ((size_t)kt*64 + l)*8);
        bfv8 hv = *(const bfv8*)(const void*)((const char*)hs + ((hbase + kt*64) ^ hswz));
        acc = mfma16(hv, wf, acc);
      }
    } else {
      #pragma unroll
      for(int kt=0;kt<32;kt++){
        bfv8 hv = *(const bfv8*)(const void*)((const char*)hs + ((hbase + kt*64) ^ hswz));
        acc = mfma16(hv, bf[kt], acc);
      }
    }
    {
      int rr = (l>>4)*4;
      #pragma unroll
      for(int q=0;q<4;q++) Gs[rr+q][wvi*16 + fr] = acc[q];
    }
    __syncthreads();
    if(tid < 256){
      float bi0=di0,bi1=di1,bf0=df0,bf1=df1,bg0=dg0,bg1=dg1,bo0=do0,bo1=do1;
      if(t==0){
        bi0=bd[hcol];      bi1=bd[hcol+1];
        bf0=bd[HH+hcol];   bf1=bd[HH+hcol+1];
        bg0=bd[2*HH+hcol]; bg1=bd[2*HH+hcol+1];
        bo0=bd[3*HH+hcol]; bo1=bd[3*HH+hcol+1];
      }
      float gi0 = Gs[lr][lc]    + bi0, gi1 = Gs[lr][lc+1] + bi1;
      float gf0 = Gs[lr][32+lc] + bf0, gf1 = Gs[lr][33+lc] + bf1;
      float gg0 = Gs[lr][64+lc] + bg0, gg1 = Gs[lr][65+lc] + bg1;
      float go0 = Gs[lr][96+lc] + bo0, go1 = Gs[lr][97+lc] + bo1;
      float c20 = sigm(gf0)*cs0 + sigm(gi0)*tanhf(gg0);
      float c21 = sigm(gf1)*cs1 + sigm(gi1)*tanhf(gg1);
      cs0 = c20; cs1 = c21;
      float h20 = sigm(go0)*tanhf(c20);
      float h21 = sigm(go1)*tanhf(c21);
      unsigned int hn = (unsigned)f2b(h20) | ((unsigned)f2b(h21)<<16);
      unsigned short* outslot = ring + (size_t)(t%100)*BB*HH;
      __hip_atomic_store((unsigned int*)(outslot + (size_t)(bg*16+lr)*HH + hcol), hn,
                         __ATOMIC_RELAXED, __HIP_MEMORY_SCOPE_AGENT);
    }
    g_arrive(cnt, gen); ge++;

    if((t%100)==99){
      g_wait(gen, ge);   // all 100 slots final
      int tbase = t - 99;
      #pragma unroll 1
      for(int s = cg; s < 100; s += 32){
        stage_h(hs, ring + (size_t)s*BB*HH, bg, tid);
        __syncthreads();
        int tout = tbase + s;
        #pragma unroll 1
        for(int pass=0; pass<2; pass++){
          int nt = (pass==0) ? wvi : 8;
          if(pass==1 && wvi!=0) break;
          const unsigned short* wsrc = WpgS + (size_t)nt*32*64*8;
          f32x4 acc = {0.f,0.f,0.f,0.f};
          #pragma unroll
          for(int kt=0;kt<32;kt++){
            bfv8 wf = *(const bfv8*)(const void*)(wsrc + ((size_t)kt*64 + l)*8);
            bfv8 hv = *(const bfv8*)(const void*)((const char*)hs + ((hbase + kt*64) ^ hswz));
            acc = mfma16(hv, wf, acc);
          }
          int n = nt*16 + fr;
          #pragma unroll
          for(int q=0;q<4;q++){
            int b = bg*16 + (l>>4)*4 + q;
            bool msk = tout > mlen[b];
            if(n < MELD)
              outmel[((size_t)b*TMEL + tout)*MELD + n] = msk ? 0.f : acc[q]+bp[n];
            else if(n == MELD)
              outgate[(size_t)b*TMEL + tout] = msk ? 1000.f : acc[q]+bgp[0];
          }
        }
        __syncthreads();
      }
      g_arrive(cnt, gen); ge++;
    }
  }
}

__global__ void k_mask(const int* __restrict__ mlen, float* __restrict__ om){
  int idx=blockIdx.x*256+threadIdx.x; if(idx>=BB*TMEL) return;
  int b=idx/TMEL, t=idx%TMEL;
  om[idx] = (t > mlen[b]) ? 1.f : 0.f;
}

extern "C" void kernel_launch(void* const* d_in, const int* in_sizes, int n_in,
                              void* d_out, int out_size, void* d_ws, size_t ws_size,
                              hipStream_t stream){
  (void)in_sizes; (void)n_in; (void)out_size; (void)ws_size;
  const int*   x    = (const int*)d_in[0];
  const int*   tlen = (const int*)d_in[1];
  const int*   mlen = (const int*)d_in[3];
  const float* emb  = (const float*)d_in[4];
  const float* elW  = (const float*)d_in[5];
  const float* elb  = (const float*)d_in[6];
  const float* c1W  = (const float*)d_in[7];
  const float* c1b  = (const float*)d_in[8];
  const float* g1   = (const float*)d_in[9];
  const float* be1  = (const float*)d_in[10];
  const float* c2W  = (const float*)d_in[11];
  const float* c2b  = (const float*)d_in[12];
  const float* g2   = (const float*)d_in[13];
  const float* be2  = (const float*)d_in[14];
  const float* Wihe = (const float*)d_in[15];
  const float* Whhe = (const float*)d_in[16];
  const float* bhe  = (const float*)d_in[17];
  const float* Wihd = (const float*)d_in[18];
  const float* Whhd = (const float*)d_in[19];
  const float* bhd  = (const float*)d_in[20];
  const float* Wp   = (const float*)d_in[21];
  const float* bp   = (const float*)d_in[22];
  const float* Wg   = (const float*)d_in[23];
  const float* bg   = (const float*)d_in[24];

  float* ws = (float*)d_ws;
  float* proj = ws + OFF_PROJ;
  float* T1   = ws + OFF_T1;
  unsigned short* Wr2b = (unsigned short*)(ws + OFF_WR2);
  float* bb1 = ws + OFF_BB1;
  float* bb2 = ws + OFF_BB2;
  float* b2  = ws + OFF_B2;
  float* W2c = ws + OFF_W2C;
  unsigned int* bar = (unsigned int*)(ws + OFF_BAR);
  unsigned short* WencR = (unsigned short*)(ws + OFF_WENCR);
  unsigned short* WihS  = (unsigned short*)(ws + OFF_WIHS);
  unsigned short* W2cR  = (unsigned short*)(ws + OFF_W2CR);
  unsigned short* WhhdS = (unsigned short*)(ws + OFF_WHHDS);
  unsigned short* WpgS  = (unsigned short*)(ws + OFF_WPGS);
  unsigned short* h2b   = (unsigned short*)(ws + OFF_H2B);
  unsigned short* h1pb  = (unsigned short*)(ws + OFF_RING); // conv scratch
  unsigned short* ring  = (unsigned short*)(ws + OFF_RING); // alias after conv2

  float* outmel  = (float*)d_out;
  float* outgate = outmel + (size_t)BB*TMEL*MELD;
  float* outmask = outgate + (size_t)BB*TMEL;

  hipMemsetAsync(bar, 0, 2048, stream);

  k_proj<<<VV,256,0,stream>>>(emb, elW, elb, proj);
  k_t1<<<dim3(VV,3),256,0,stream>>>(proj, c1W, g1, T1);
  k_wr2<<<(EE*3*EE+255)/256,256,0,stream>>>(c2W, g2, Wr2b);
  k_bb<<<2,256,0,stream>>>(c1b,g1,be1,c2b,g2,be2,bb1,bb2);
  k_b2<<<16,256,0,stream>>>(bhd, Wihd, bp, b2);
  k_w2c<<<dim3(4096/8,HH/256),256,0,stream>>>(Whhd, Wihd, Wp, W2c);
  k_pack<<<256,256,0,stream>>>(Whhe, WencR, 32, 1024);
  k_pack<<<256,256,0,stream>>>(Wihe, WihS, 16, 512);
  k_pack<<<256,256,0,stream>>>(W2c,  W2cR, 32, 1024);
  k_pack<<<256,256,0,stream>>>(Whhd, WhhdS, 32, 1024);
  k_pack_pg<<<9,256,0,stream>>>(Wp, Wg, WpgS);
  k_pad<<<256,256,0,stream>>>(h1pb);
  k_conv1<<<65536,256,0,stream>>>(x, T1, bb1, h1pb);
  k_conv2mm<<<dim3(BB,2,32),256,0,stream>>>(h1pb, Wr2b, bb2, h2b);

  void* kargs[] = {
    (void*)&h2b, (void*)&ring, (void*)&WencR, (void*)&WihS, (void*)&W2cR, (void*)&WhhdS,
    (void*)&WpgS, (void*)&bhe, (void*)&bhd, (void*)&b2, (void*)&bp, (void*)&bg,
    (void*)&bar, (void*)&tlen, (void*)&mlen, (void*)&outmel, (void*)&outgate
  };
  hipLaunchCooperativeKernel((void*)k_recur, dim3(256), dim3(512), kargs, 0u, stream);

  k_mask<<<(BB*TMEL+255)/256,256,0,stream>>>(mlen, outmask);
}